// Round 14
// baseline (31780.746 us; speedup 1.0000x reference)
//
#include <hip/hip_runtime.h>
#include <hip/hip_bf16.h>
#include <math.h>

#define S_LEN 4096
#define HID   1024
#define G4H   4096
#define EDIM  300
#define VOC   32000
#define NWG_LSTM 64       // LSTM workgroups (barrier participants) — r13: 128->64
#define HPW_L 16          // h units per workgroup
#define FLAG_STRIDE 32    // ints (128B) between flags
#define NPART 25          // vocab parts for loss kernel (25 * 1280 = 32000)
#define NPCOL 50          // partial columns = NPART * 2 wave-halves

typedef __attribute__((ext_vector_type(8))) short bf16x8;
typedef __attribute__((ext_vector_type(4))) float f32x4;

__device__ __forceinline__ float bf_lo(unsigned u){ return __uint_as_float(u << 16); }
__device__ __forceinline__ float bf_hi(unsigned u){ return __uint_as_float(u & 0xffff0000u); }
__device__ __forceinline__ unsigned short f2bf(float x){
  unsigned u = __float_as_uint(x);
  unsigned r = (u + 0x7fffu + ((u >> 16) & 1u)) >> 16;
  return (unsigned short)r;
}

// ---------------------------------------------------------------------------
// fp32 -> bf16 conversion, 8 elems/thread
// ---------------------------------------------------------------------------
__global__ __launch_bounds__(256) void conv_bf16_kernel(
    const float* __restrict__ in, unsigned short* __restrict__ out, int n8)
{
  for (int i = blockIdx.x * blockDim.x + threadIdx.x; i < n8;
       i += gridDim.x * blockDim.x) {
    const float4* p = (const float4*)(in + (size_t)i * 8);
    float4 a = p[0], b = p[1];
    uint4 o;
    o.x = (unsigned)f2bf(a.x) | ((unsigned)f2bf(a.y) << 16);
    o.y = (unsigned)f2bf(a.z) | ((unsigned)f2bf(a.w) << 16);
    o.z = (unsigned)f2bf(b.x) | ((unsigned)f2bf(b.y) << 16);
    o.w = (unsigned)f2bf(b.z) | ((unsigned)f2bf(b.w) << 16);
    *(uint4*)(out + (size_t)i * 8) = o;
  }
}

// ---------------------------------------------------------------------------
// Generic C = A @ B^T + bias1 (+bias2), A rows optionally gathered.
// ---------------------------------------------------------------------------
template<int BM, int BN, int BK, int TM, int TN, bool GATHER, bool HASB2>
__global__ __launch_bounds__(256) void gemm_abt(
    const float* __restrict__ A, int lda, const int* __restrict__ gidx,
    const float* __restrict__ B, int ldb,
    const float* __restrict__ bias1, const float* __restrict__ bias2,
    float* __restrict__ C, int ldc, int K)
{
  __shared__ float As[BK][BM + 1];
  __shared__ float Bs[BK][BN + 1];
  const int tid = threadIdx.x;
  const int tx = tid & 15, ty = tid >> 4;
  const int m0 = blockIdx.x * BM, n0 = blockIdx.y * BN;

  float acc[TM][TN];
#pragma unroll
  for (int i = 0; i < TM; i++)
#pragma unroll
    for (int j = 0; j < TN; j++) acc[i][j] = 0.f;

  for (int k0 = 0; k0 < K; k0 += BK) {
    for (int e = tid; e < BM * BK; e += 256) {
      int kk = e & (BK - 1); int m = e / BK;
      int k = k0 + kk;
      int row = GATHER ? gidx[m0 + m] : (m0 + m);
      As[kk][m] = (k < K) ? A[(size_t)row * lda + k] : 0.f;
    }
    for (int e = tid; e < BN * BK; e += 256) {
      int kk = e & (BK - 1); int n = e / BK;
      int k = k0 + kk;
      Bs[kk][n] = (k < K) ? B[(size_t)(n0 + n) * ldb + k] : 0.f;
    }
    __syncthreads();
#pragma unroll
    for (int kk = 0; kk < BK; kk++) {
      float a[TM], b[TN];
#pragma unroll
      for (int i = 0; i < TM; i++) a[i] = As[kk][ty + i * 16];
#pragma unroll
      for (int j = 0; j < TN; j++) b[j] = Bs[kk][tx + j * 16];
#pragma unroll
      for (int i = 0; i < TM; i++)
#pragma unroll
        for (int j = 0; j < TN; j++) acc[i][j] = fmaf(a[i], b[j], acc[i][j]);
    }
    __syncthreads();
  }
#pragma unroll
  for (int i = 0; i < TM; i++)
#pragma unroll
    for (int j = 0; j < TN; j++) {
      int m = m0 + ty + i * 16, n = n0 + tx + j * 16;
      float v = acc[i][j] + bias1[n];
      if (HASB2) v += bias2[n];
      C[(size_t)m * ldc + n] = v;
    }
}

// ---------------------------------------------------------------------------
// Persistent LSTM scan, cooperative launch. 64 WGs x 256 threads.
// r4 sync structure with HALF the barrier participants (128->64):
//  - 64 strided flags (128B apart); ALL 4 waves poll independently + s_sleep;
//    one atomic load per poll round (64 lanes <-> 64 flags)
//  - h gather via plain coalesced float4 loads (r12-validated, absmax 0.0)
//  - wave v = gate v, 16 rows of W_hh in VGPRs (128 u32 packed bf16)
//  - finisher tid<16 with FAST transcendentals (__expf / __fdividef) --
//    they sit on the release critical path
//  - RELEASE flag store by tid==0 (same wave as h stores; vmcnt drain orders)
// ---------------------------------------------------------------------------
__global__ __launch_bounds__(256) void lstm_kernel(
    const float* __restrict__ Gx,   // [4096][4096] x-part + both biases
    const float* __restrict__ Whh,  // [4096][1024]
    float* __restrict__ Hs,         // [4096][1024]
    int* __restrict__ flags)        // NWG_LSTM * FLAG_STRIDE ints, zeroed
{
  const int wg = blockIdx.x;       // 0..63
  const int tid = threadIdx.x;
  const int v = tid >> 6;          // wave id == gate id (0:i 1:f 2:g 3:o)
  const int lane = tid & 63;

  __shared__ float gsum[4][HPW_L];

  // weight pack matched to float4 h layout: lane owns h[i*256 + 4*lane .. +3]
  unsigned wreg[128];
  {
    const float4* W4 = reinterpret_cast<const float4*>(Whh);
#pragma unroll
    for (int r = 0; r < HPW_L; r++) {
      int row = v * HID + wg * HPW_L + r;
#pragma unroll
      for (int i = 0; i < 4; i++) {
        float4 w = W4[(size_t)row * 256 + i * 64 + lane];
        wreg[r * 8 + i * 2]     = ((unsigned)f2bf(w.y) << 16) | (unsigned)f2bf(w.x);
        wreg[r * 8 + i * 2 + 1] = ((unsigned)f2bf(w.w) << 16) | (unsigned)f2bf(w.z);
      }
    }
  }
  float creg = 0.f;   // c-state, lanes<16 of wave 0 only

  for (int t = 0; t < S_LEN; t++) {
    // prefetch Gx for finishers (normal cached loads, in flight during poll)
    float gx0 = 0.f, gx1 = 0.f, gx2 = 0.f, gx3 = 0.f;
    if (tid < HPW_L) {
      size_t b = (size_t)t * G4H + wg * HPW_L + tid;
      gx0 = Gx[b];
      gx1 = Gx[b + 1024];
      gx2 = Gx[b + 2048];
      gx3 = Gx[b + 3072];
    }
    if (t > 0) {
      while (true) {
        int f = __hip_atomic_load(&flags[lane * FLAG_STRIDE], __ATOMIC_RELAXED,
                                  __HIP_MEMORY_SCOPE_AGENT);
        if (__all(f >= t)) break;
        __builtin_amdgcn_s_sleep(1);
      }
      asm volatile("" ::: "memory");   // compiler-only: keep h loads below poll
    }

    float hv[16];
    if (t > 0) {
      const float4* hp4 = (const float4*)(Hs + (size_t)(t - 1) * HID);
#pragma unroll
      for (int i = 0; i < 4; i++) {
        float4 h4 = hp4[i * 64 + lane];
        hv[4 * i + 0] = h4.x;
        hv[4 * i + 1] = h4.y;
        hv[4 * i + 2] = h4.z;
        hv[4 * i + 3] = h4.w;
      }
    } else {
#pragma unroll
      for (int i = 0; i < 16; i++) hv[i] = 0.f;
    }

#pragma unroll
    for (int r = 0; r < HPW_L; r++) {
      float acc = 0.f;
#pragma unroll
      for (int i = 0; i < 4; i++) {
        unsigned w0 = wreg[r * 8 + i * 2];
        unsigned w1 = wreg[r * 8 + i * 2 + 1];
        acc = fmaf(bf_lo(w0), hv[4 * i + 0], acc);
        acc = fmaf(bf_hi(w0), hv[4 * i + 1], acc);
        acc = fmaf(bf_lo(w1), hv[4 * i + 2], acc);
        acc = fmaf(bf_hi(w1), hv[4 * i + 3], acc);
      }
#pragma unroll
      for (int off = 1; off < 64; off <<= 1) acc += __shfl_xor(acc, off, 64);
      if (lane == 0) gsum[v][r] = acc;
    }
    __syncthreads();

    if (tid < HPW_L) {
      const int hu = tid;
      float gi = gsum[0][hu] + gx0;
      float gf = gsum[1][hu] + gx1;
      float gg = gsum[2][hu] + gx2;
      float go = gsum[3][hu] + gx3;
      // fast transcendentals (on the release critical path)
      float i_ = __fdividef(1.f, 1.f + __expf(-gi));
      float f_ = __fdividef(1.f, 1.f + __expf(-gf));
      float eg = __expf(2.f * gg);
      float g_ = __fdividef(eg - 1.f, eg + 1.f);
      float o_ = __fdividef(1.f, 1.f + __expf(-go));
      float c = f_ * creg + i_ * g_;
      creg = c;
      float ec = __expf(2.f * c);
      float h = o_ * __fdividef(ec - 1.f, ec + 1.f);
      __hip_atomic_store(&Hs[(size_t)t * HID + wg * HPW_L + hu], h,
                         __ATOMIC_RELAXED, __HIP_MEMORY_SCOPE_AGENT);
    }
    // release by lane 0 of the SAME wave that issued the h stores:
    // vmcnt(0) drain orders them before the flag at the LLC.
    if (tid == 0) {
      __hip_atomic_store(&flags[wg * FLAG_STRIDE], t + 1,
                         __ATOMIC_RELEASE, __HIP_MEMORY_SCOPE_AGENT);
    }
  }
}

// ---------------------------------------------------------------------------
// GCN: Cu[i][d] = tanh(Cu + sum_{j<i} D[j][i]*Hd[j][d] + sum_{j<i} D[i][j]*Md[j][d])
// ---------------------------------------------------------------------------
__global__ __launch_bounds__(256) void gcn_kernel(
    const float* __restrict__ dep,   // (S+1)x(S+1)
    const float* __restrict__ Hd, const float* __restrict__ Md,
    float* __restrict__ Cu)
{
  const int BM = 128, BN = 64, BK = 8, TM = 8, TN = 4;
  __shared__ float Dc[BK][BM + 1];
  __shared__ float Dr[BK][BM + 1];
  __shared__ float Bh[BK][BN + 1];
  __shared__ float Bm[BK][BN + 1];
  const int tid = threadIdx.x, tx = tid & 15, ty = tid >> 4;
  const int i0 = blockIdx.x * BM, d0 = blockIdx.y * BN;

  float acc1[TM][TN], acc2[TM][TN];
#pragma unroll
  for (int i = 0; i < TM; i++)
#pragma unroll
    for (int j = 0; j < TN; j++) { acc1[i][j] = 0.f; acc2[i][j] = 0.f; }

  const int jmax = i0 + BM;   // strict mask j<i kills everything beyond
  for (int j0 = 0; j0 < jmax; j0 += BK) {
    for (int e = tid; e < BM * BK; e += 256) {          // column of D, m-fast
      int m = e & (BM - 1), kk = e >> 7;
      int j = j0 + kk, ii = i0 + m;
      Dc[kk][m] = (j < ii) ? dep[(size_t)j * (S_LEN + 1) + ii] : 0.f;
    }
    for (int e = tid; e < BM * BK; e += 256) {          // row of D, kk-fast
      int kk = e & (BK - 1), m = e >> 3;
      int j = j0 + kk, ii = i0 + m;
      Dr[kk][m] = (j < ii) ? dep[(size_t)ii * (S_LEN + 1) + j] : 0.f;
    }
    for (int e = tid; e < BN * BK; e += 256) {
      int n = e & (BN - 1), kk = e >> 6;
      int j = j0 + kk;
      Bh[kk][n] = Hd[(size_t)j * HID + d0 + n];
      Bm[kk][n] = Md[(size_t)j * HID + d0 + n];
    }
    __syncthreads();
#pragma unroll
    for (int kk = 0; kk < BK; kk++) {
      float a1[TM], a2[TM], b1[TN], b2[TN];
#pragma unroll
      for (int i = 0; i < TM; i++) { a1[i] = Dc[kk][ty + i * 16]; a2[i] = Dr[kk][ty + i * 16]; }
#pragma unroll
      for (int j = 0; j < TN; j++) { b1[j] = Bh[kk][tx + j * 16]; b2[j] = Bm[kk][tx + j * 16]; }
#pragma unroll
      for (int i = 0; i < TM; i++)
#pragma unroll
        for (int j = 0; j < TN; j++) {
          acc1[i][j] = fmaf(a1[i], b1[j], acc1[i][j]);
          acc2[i][j] = fmaf(a2[i], b2[j], acc2[i][j]);
        }
    }
    __syncthreads();
  }
#pragma unroll
  for (int i = 0; i < TM; i++)
#pragma unroll
    for (int j = 0; j < TN; j++) {
      int m = i0 + ty + i * 16, n = d0 + tx + j * 16;
      size_t idx = (size_t)m * HID + n;
      Cu[idx] = tanhf(Cu[idx] + acc1[i][j] + acc2[i][j]);
    }
}

// ---------------------------------------------------------------------------
// MFMA bf16 fused vocab GEMM + online log-softmax partials.
// Grid (32 row-blocks, 25 parts); 256 thr = 4 waves in 2x2; tile 128x128, BK=64.
// ---------------------------------------------------------------------------
__global__ __launch_bounds__(256) void loss_mfma_kernel(
    const unsigned short* __restrict__ Gbf,   // [4096][1024] bf16
    const unsigned short* __restrict__ Wobf,  // [32000][1024] bf16
    const float* __restrict__ bo, const int* __restrict__ tokens,
    float* __restrict__ pm, float* __restrict__ ps, float* __restrict__ pt)
{
  __shared__ unsigned short As[128 * 72];
  __shared__ unsigned short Bs[128 * 72];
  const int tid = threadIdx.x;
  const int lane = tid & 63;
  const int wid = tid >> 6;
  const int wm = wid >> 1;        // row half (0..1)
  const int wn = wid & 1;         // col half (0..1)
  const int lrow = lane & 15;
  const int lkg  = lane >> 4;     // 0..3
  const int i0 = blockIdx.x * 128;
  const int part = blockIdx.y;
  const int nbase = part * 1280;

  float rmax[4][4], rsum[4][4], tsum[4][4];
  int tg[4][4];
#pragma unroll
  for (int mt = 0; mt < 4; mt++)
#pragma unroll
    for (int r = 0; r < 4; r++) {
      rmax[mt][r] = -1e30f; rsum[mt][r] = 0.f; tsum[mt][r] = 0.f;
      tg[mt][r] = tokens[1 + i0 + wm * 64 + mt * 16 + lkg * 4 + r];
    }

  for (int c = 0; c < 10; c++) {
    const int n0 = nbase + c * 128;
    f32x4 acc[4][4];
#pragma unroll
    for (int mt = 0; mt < 4; mt++)
#pragma unroll
      for (int nt = 0; nt < 4; nt++) acc[mt][nt] = (f32x4){0.f, 0.f, 0.f, 0.f};

    for (int k0 = 0; k0 < HID; k0 += 64) {
#pragma unroll
      for (int it = 0; it < 4; it++) {
        int idx = it * 256 + tid;
        int row = idx >> 3, col8 = (idx & 7) * 8;
        *(uint4*)&As[row * 72 + col8] =
            *(const uint4*)&Gbf[(size_t)(i0 + row) * HID + k0 + col8];
        *(uint4*)&Bs[row * 72 + col8] =
            *(const uint4*)&Wobf[(size_t)(n0 + row) * HID + k0 + col8];
      }
      __syncthreads();
#pragma unroll
      for (int ks = 0; ks < 2; ks++) {
        const int kk = ks * 32 + lkg * 8;
        bf16x8 a[4], b[4];
#pragma unroll
        for (int mt = 0; mt < 4; mt++)
          a[mt] = *(const bf16x8*)&As[(wm * 64 + mt * 16 + lrow) * 72 + kk];
#pragma unroll
        for (int nt = 0; nt < 4; nt++)
          b[nt] = *(const bf16x8*)&Bs[(wn * 64 + nt * 16 + lrow) * 72 + kk];
#pragma unroll
        for (int mt = 0; mt < 4; mt++)
#pragma unroll
          for (int nt = 0; nt < 4; nt++)
            acc[mt][nt] = __builtin_amdgcn_mfma_f32_16x16x32_bf16(
                a[mt], b[nt], acc[mt][nt], 0, 0, 0);
      }
      __syncthreads();
    }

    // bias + online softmax update
    float bov[4];
#pragma unroll
    for (int nt = 0; nt < 4; nt++)
      bov[nt] = bo[n0 + wn * 64 + nt * 16 + lrow];

#pragma unroll
    for (int mt = 0; mt < 4; mt++)
#pragma unroll
      for (int r = 0; r < 4; r++) {
        float v0 = acc[mt][0][r] + bov[0];
        float v1 = acc[mt][1][r] + bov[1];
        float v2 = acc[mt][2][r] + bov[2];
        float v3 = acc[mt][3][r] + bov[3];
        float cm = fmaxf(fmaxf(v0, v1), fmaxf(v2, v3));
#pragma unroll
        for (int off = 1; off < 16; off <<= 1) cm = fmaxf(cm, __shfl_xor(cm, off, 64));
        float nm = fmaxf(rmax[mt][r], cm);
        float sp = __expf(v0 - nm) + __expf(v1 - nm) + __expf(v2 - nm) + __expf(v3 - nm);
#pragma unroll
        for (int off = 1; off < 16; off <<= 1) sp += __shfl_xor(sp, off, 64);
        rsum[mt][r] = rsum[mt][r] * __expf(rmax[mt][r] - nm) + sp;
        rmax[mt][r] = nm;
        // target logit pick
        int nc = n0 + wn * 64 + lrow;
        if (nc       == tg[mt][r]) tsum[mt][r] += v0;
        if (nc + 16  == tg[mt][r]) tsum[mt][r] += v1;
        if (nc + 32  == tg[mt][r]) tsum[mt][r] += v2;
        if (nc + 48  == tg[mt][r]) tsum[mt][r] += v3;
      }
  }

  // write partials (one column-half per wave): p in [0, 50)
  const int p = part * 2 + wn;
#pragma unroll
  for (int mt = 0; mt < 4; mt++)
#pragma unroll
    for (int r = 0; r < 4; r++) {
      float tv = tsum[mt][r];
#pragma unroll
      for (int off = 1; off < 16; off <<= 1) tv += __shfl_xor(tv, off, 64);
      if (lrow == 0) {
        int m = i0 + wm * 64 + mt * 16 + lkg * 4 + r;
        pm[p * S_LEN + m] = rmax[mt][r];
        ps[p * S_LEN + m] = rsum[mt][r];
        pt[p * S_LEN + m] = tv;
      }
    }
}

// ---------------------------------------------------------------------------
// Combine partials across the NPCOL column-partials -> mean NLL
// ---------------------------------------------------------------------------
__global__ __launch_bounds__(256) void combine_kernel(
    const float* __restrict__ pm, const float* __restrict__ ps,
    const float* __restrict__ pt, float* __restrict__ out)
{
  const int tid = threadIdx.x;
  float lsum = 0.f;
  for (int r = tid; r < S_LEN; r += 256) {
    float M = -1e30f;
    for (int p = 0; p < NPCOL; p++) M = fmaxf(M, pm[p * S_LEN + r]);
    float S = 0.f, tv = 0.f;
    for (int p = 0; p < NPCOL; p++) {
      S += ps[p * S_LEN + r] * expf(pm[p * S_LEN + r] - M);
      tv += pt[p * S_LEN + r];
    }
    lsum += (M + logf(S)) - tv;
  }
  __shared__ float red[256];
  red[tid] = lsum;
  __syncthreads();
  for (int s = 128; s > 0; s >>= 1) {
    if (tid < s) red[tid] += red[tid + s];
    __syncthreads();
  }
  if (tid == 0) out[0] = red[0] / (float)S_LEN;
}

// ---------------------------------------------------------------------------
extern "C" void kernel_launch(void* const* d_in, const int* in_sizes, int n_in,
                              void* d_out, int out_size, void* d_ws, size_t ws_size,
                              hipStream_t stream)
{
  const float* dep = (const float*)d_in[0];
  const float* emb = (const float*)d_in[1];
  const float* Wih = (const float*)d_in[2];
  const float* Whh = (const float*)d_in[3];
  const float* bih = (const float*)d_in[4];
  const float* bhh = (const float*)d_in[5];
  const float* Wh  = (const float*)d_in[6];
  const float* bh  = (const float*)d_in[7];
  const float* Wm  = (const float*)d_in[8];
  const float* bm  = (const float*)d_in[9];
  const float* Wc  = (const float*)d_in[10];
  const float* bc  = (const float*)d_in[11];
  const float* Wo  = (const float*)d_in[12];
  const float* bo  = (const float*)d_in[13];
  const int*   tok = (const int*)d_in[14];
  float* out = (float*)d_out;

  float* ws = (float*)d_ws;
  size_t o = 0;
  float* Gx = ws + o; o += (size_t)S_LEN * G4H;    // 67 MB; dead after lstm
  float* Hs = ws + o; o += (size_t)S_LEN * HID;
  float* Hd = ws + o; o += (size_t)S_LEN * HID;
  float* Md = ws + o; o += (size_t)S_LEN * HID;
  float* Cu = ws + o; o += (size_t)S_LEN * HID;
  float* pm = ws + o; o += (size_t)NPCOL * S_LEN;
  float* ps_ = ws + o; o += (size_t)NPCOL * S_LEN;
  float* pt_ = ws + o; o += (size_t)NPCOL * S_LEN;
  unsigned short* Gbf = (unsigned short*)(ws + o); o += (size_t)S_LEN * HID / 2;
  int* flags = (int*)(ws + o);
  // Wobf aliases Gx (65.5 MB <= 67 MB), written only after lstm_kernel finished
  unsigned short* Wobf = (unsigned short*)Gx;

  hipMemsetAsync(flags, 0, NWG_LSTM * FLAG_STRIDE * sizeof(int), stream);

  dim3 blk(256);
  // Gx = emb[tok] @ W_ih^T + b_ih + b_hh
  gemm_abt<128, 128, 16, 8, 8, true, true><<<dim3(32, 32), blk, 0, stream>>>(
      emb, EDIM, tok, Wih, EDIM, bih, bhh, Gx, G4H, EDIM);

  // sequential LSTM — cooperative launch, 64 WGs x 256 threads
  {
    void* args[] = {(void*)&Gx, (void*)&Whh, (void*)&Hs, (void*)&flags};
    hipLaunchCooperativeKernel((const void*)lstm_kernel, dim3(NWG_LSTM),
                               dim3(256), args, 0, stream);
  }

  // Wo -> bf16 (into Gx's space; safe after lstm)
  conv_bf16_kernel<<<dim3(2048), blk, 0, stream>>>(Wo, Wobf, VOC * HID / 8);

  // three projections
  gemm_abt<128, 128, 16, 8, 8, false, false><<<dim3(32, 8), blk, 0, stream>>>(
      Hs, HID, nullptr, Wh, HID, bh, nullptr, Hd, HID, HID);
  gemm_abt<128, 128, 16, 8, 8, false, false><<<dim3(32, 8), blk, 0, stream>>>(
      Hs, HID, nullptr, Wm, HID, bm, nullptr, Md, HID, HID);
  gemm_abt<128, 128, 16, 8, 8, false, false><<<dim3(32, 8), blk, 0, stream>>>(
      Hs, HID, nullptr, Wc, HID, bc, nullptr, Cu, HID, HID);
  // GCN + tanh (in-place into Cu)
  gcn_kernel<<<dim3(32, 16), blk, 0, stream>>>(dep, Hd, Md, Cu);
  // GCN output -> bf16
  conv_bf16_kernel<<<dim3(2048), blk, 0, stream>>>(Cu, Gbf, S_LEN * HID / 8);
  // fused MFMA vocab GEMM + online log-softmax partials
  loss_mfma_kernel<<<dim3(32, NPART), blk, 0, stream>>>(
      Gbf, Wobf, bo, tok, pm, ps_, pt_);
  // combine -> scalar loss
  combine_kernel<<<dim3(1), blk, 0, stream>>>(pm, ps_, pt_, out);
}

// Round 15
// 25408.994 us; speedup vs baseline: 1.2508x; 1.2508x over previous
//
#include <hip/hip_runtime.h>
#include <hip/hip_bf16.h>
#include <math.h>

#define S_LEN 4096
#define HID   1024
#define G4H   4096
#define EDIM  300
#define VOC   32000
#define NWG_LSTM 128      // LSTM workgroups (r12 proven config)
#define HPW   8           // h units per workgroup
#define FLAG_STRIDE 32    // ints (128B) between flags
#define NPART 25          // vocab parts for loss kernel (25 * 1280 = 32000)
#define NPCOL 50          // partial columns = NPART * 2 wave-halves

typedef __attribute__((ext_vector_type(8))) short bf16x8;
typedef __attribute__((ext_vector_type(4))) float f32x4;

__device__ __forceinline__ float bf_lo(unsigned u){ return __uint_as_float(u << 16); }
__device__ __forceinline__ float bf_hi(unsigned u){ return __uint_as_float(u & 0xffff0000u); }
__device__ __forceinline__ unsigned short f2bf(float x){
  unsigned u = __float_as_uint(x);
  unsigned r = (u + 0x7fffu + ((u >> 16) & 1u)) >> 16;
  return (unsigned short)r;
}

// ---------------------------------------------------------------------------
// fp32 -> bf16 conversion, 8 elems/thread
// ---------------------------------------------------------------------------
__global__ __launch_bounds__(256) void conv_bf16_kernel(
    const float* __restrict__ in, unsigned short* __restrict__ out, int n8)
{
  for (int i = blockIdx.x * blockDim.x + threadIdx.x; i < n8;
       i += gridDim.x * blockDim.x) {
    const float4* p = (const float4*)(in + (size_t)i * 8);
    float4 a = p[0], b = p[1];
    uint4 o;
    o.x = (unsigned)f2bf(a.x) | ((unsigned)f2bf(a.y) << 16);
    o.y = (unsigned)f2bf(a.z) | ((unsigned)f2bf(a.w) << 16);
    o.z = (unsigned)f2bf(b.x) | ((unsigned)f2bf(b.y) << 16);
    o.w = (unsigned)f2bf(b.z) | ((unsigned)f2bf(b.w) << 16);
    *(uint4*)(out + (size_t)i * 8) = o;
  }
}

// ---------------------------------------------------------------------------
// Generic C = A @ B^T + bias1 (+bias2), A rows optionally gathered. (Gx only)
// ---------------------------------------------------------------------------
template<int BM, int BN, int BK, int TM, int TN, bool GATHER, bool HASB2>
__global__ __launch_bounds__(256) void gemm_abt(
    const float* __restrict__ A, int lda, const int* __restrict__ gidx,
    const float* __restrict__ B, int ldb,
    const float* __restrict__ bias1, const float* __restrict__ bias2,
    float* __restrict__ C, int ldc, int K)
{
  __shared__ float As[BK][BM + 1];
  __shared__ float Bs[BK][BN + 1];
  const int tid = threadIdx.x;
  const int tx = tid & 15, ty = tid >> 4;
  const int m0 = blockIdx.x * BM, n0 = blockIdx.y * BN;

  float acc[TM][TN];
#pragma unroll
  for (int i = 0; i < TM; i++)
#pragma unroll
    for (int j = 0; j < TN; j++) acc[i][j] = 0.f;

  for (int k0 = 0; k0 < K; k0 += BK) {
    for (int e = tid; e < BM * BK; e += 256) {
      int kk = e & (BK - 1); int m = e / BK;
      int k = k0 + kk;
      int row = GATHER ? gidx[m0 + m] : (m0 + m);
      As[kk][m] = (k < K) ? A[(size_t)row * lda + k] : 0.f;
    }
    for (int e = tid; e < BN * BK; e += 256) {
      int kk = e & (BK - 1); int n = e / BK;
      int k = k0 + kk;
      Bs[kk][n] = (k < K) ? B[(size_t)(n0 + n) * ldb + k] : 0.f;
    }
    __syncthreads();
#pragma unroll
    for (int kk = 0; kk < BK; kk++) {
      float a[TM], b[TN];
#pragma unroll
      for (int i = 0; i < TM; i++) a[i] = As[kk][ty + i * 16];
#pragma unroll
      for (int j = 0; j < TN; j++) b[j] = Bs[kk][tx + j * 16];
#pragma unroll
      for (int i = 0; i < TM; i++)
#pragma unroll
        for (int j = 0; j < TN; j++) acc[i][j] = fmaf(a[i], b[j], acc[i][j]);
    }
    __syncthreads();
  }
#pragma unroll
  for (int i = 0; i < TM; i++)
#pragma unroll
    for (int j = 0; j < TN; j++) {
      int m = m0 + ty + i * 16, n = n0 + tx + j * 16;
      float v = acc[i][j] + bias1[n];
      if (HASB2) v += bias2[n];
      C[(size_t)m * ldc + n] = v;
    }
}

// ---------------------------------------------------------------------------
// Persistent LSTM scan — EXACT r12 configuration (measured 22.45 ms steady):
// 128 WGs x 256 thr; strided flags; all-wave poll + s_sleep; float4 h gather;
// RELEASE flag store. Do not touch.
// ---------------------------------------------------------------------------
__global__ __launch_bounds__(256) void lstm_kernel(
    const float* __restrict__ Gx,   // [4096][4096] x-part + both biases
    const float* __restrict__ Whh,  // [4096][1024]
    float* __restrict__ Hs,         // [4096][1024]
    int* __restrict__ flags)        // NWG_LSTM * FLAG_STRIDE ints, zeroed
{
  const int wg = blockIdx.x;
  const int tid = threadIdx.x;
  const int v = tid >> 6;       // wave id == gate id (0:i 1:f 2:g 3:o)
  const int lane = tid & 63;

  __shared__ float gsum[4][HPW];

  // weight pack matched to float4 h layout: lane owns h[i*256 + 4*lane .. +3]
  unsigned wreg[64];
  {
    const float4* W4 = reinterpret_cast<const float4*>(Whh);
#pragma unroll
    for (int r = 0; r < 8; r++) {
      int row = v * HID + wg * HPW + r;
#pragma unroll
      for (int i = 0; i < 4; i++) {
        float4 w = W4[(size_t)row * 256 + i * 64 + lane];
        wreg[r * 8 + i * 2]     = ((unsigned)f2bf(w.y) << 16) | (unsigned)f2bf(w.x);
        wreg[r * 8 + i * 2 + 1] = ((unsigned)f2bf(w.w) << 16) | (unsigned)f2bf(w.z);
      }
    }
  }
  float creg = 0.f;   // c-state, lanes<8 of wave 0 only

  for (int t = 0; t < S_LEN; t++) {
    float gx0 = 0.f, gx1 = 0.f, gx2 = 0.f, gx3 = 0.f;
    if (tid < HPW) {
      size_t b = (size_t)t * G4H + wg * HPW + tid;
      gx0 = Gx[b];
      gx1 = Gx[b + 1024];
      gx2 = Gx[b + 2048];
      gx3 = Gx[b + 3072];
    }
    if (t > 0) {
      const int i0 = lane * FLAG_STRIDE;
      const int i1 = (lane + 64) * FLAG_STRIDE;
      while (true) {
        int f0 = __hip_atomic_load(&flags[i0], __ATOMIC_RELAXED, __HIP_MEMORY_SCOPE_AGENT);
        int f1 = __hip_atomic_load(&flags[i1], __ATOMIC_RELAXED, __HIP_MEMORY_SCOPE_AGENT);
        if (__all(f0 >= t && f1 >= t)) break;
        __builtin_amdgcn_s_sleep(1);
      }
      asm volatile("" ::: "memory");
    }

    float hv[16];
    if (t > 0) {
      const float4* hp4 = (const float4*)(Hs + (size_t)(t - 1) * HID);
#pragma unroll
      for (int i = 0; i < 4; i++) {
        float4 h4 = hp4[i * 64 + lane];
        hv[4 * i + 0] = h4.x;
        hv[4 * i + 1] = h4.y;
        hv[4 * i + 2] = h4.z;
        hv[4 * i + 3] = h4.w;
      }
    } else {
#pragma unroll
      for (int i = 0; i < 16; i++) hv[i] = 0.f;
    }

#pragma unroll
    for (int r = 0; r < 8; r++) {
      float acc = 0.f;
#pragma unroll
      for (int i = 0; i < 4; i++) {
        unsigned w0 = wreg[r * 8 + i * 2];
        unsigned w1 = wreg[r * 8 + i * 2 + 1];
        acc = fmaf(bf_lo(w0), hv[4 * i + 0], acc);
        acc = fmaf(bf_hi(w0), hv[4 * i + 1], acc);
        acc = fmaf(bf_lo(w1), hv[4 * i + 2], acc);
        acc = fmaf(bf_hi(w1), hv[4 * i + 3], acc);
      }
#pragma unroll
      for (int off = 1; off < 64; off <<= 1) acc += __shfl_xor(acc, off, 64);
      if (lane == 0) gsum[v][r] = acc;
    }
    __syncthreads();

    if (tid < HPW) {
      const int hu = tid;
      float gi = gsum[0][hu] + gx0;
      float gf = gsum[1][hu] + gx1;
      float gg = gsum[2][hu] + gx2;
      float go = gsum[3][hu] + gx3;
      float i_ = 1.f / (1.f + expf(-gi));
      float f_ = 1.f / (1.f + expf(-gf));
      float g_ = tanhf(gg);
      float o_ = 1.f / (1.f + expf(-go));
      float c = f_ * creg + i_ * g_;
      creg = c;
      float h = o_ * tanhf(c);
      __hip_atomic_store(&Hs[(size_t)t * HID + wg * HPW + hu], h,
                         __ATOMIC_RELAXED, __HIP_MEMORY_SCOPE_AGENT);
    }
    if (tid == 0) {
      __hip_atomic_store(&flags[wg * FLAG_STRIDE], t + 1,
                         __ATOMIC_RELEASE, __HIP_MEMORY_SCOPE_AGENT);
    }
  }
}

// ---------------------------------------------------------------------------
// MFMA projections: C[m][n] = Hbf[m][:] . Wpbf[n][:], m=seq 4096, n=0..3071
// (Wh;Wm;Wc stacked). seg 0/1 write TRANSPOSED bf16 (HdT/MdT [1024][4096]);
// seg 2 writes Cu fp32 [4096][1024]. Core cloned from validated loss kernel.
// ---------------------------------------------------------------------------
__global__ __launch_bounds__(256) void proj_mfma_kernel(
    const unsigned short* __restrict__ Hbf,   // [4096][1024]
    const unsigned short* __restrict__ Wpbf,  // [3072][1024]
    const float* __restrict__ bh, const float* __restrict__ bm,
    const float* __restrict__ bc,
    unsigned short* __restrict__ HdT,         // [1024][4096] bf16
    unsigned short* __restrict__ MdT,         // [1024][4096] bf16
    float* __restrict__ Cu)                   // [4096][1024] fp32
{
  __shared__ unsigned short As[128 * 72];
  __shared__ unsigned short Bs[128 * 72];
  const int tid = threadIdx.x;
  const int lane = tid & 63;
  const int wid = tid >> 6;
  const int wm = wid >> 1, wn = wid & 1;
  const int lrow = lane & 15, lkg = lane >> 4;
  const int i0 = blockIdx.x * 128;
  const int nb = blockIdx.y;            // 0..23
  const int n0 = nb * 128;              // row into Wpbf
  const int seg = nb >> 3;              // 0:Wh 1:Wm 2:Wc
  const int nloc0 = (nb & 7) * 128;     // col base within segment

  f32x4 acc[4][4];
#pragma unroll
  for (int mt = 0; mt < 4; mt++)
#pragma unroll
    for (int nt = 0; nt < 4; nt++) acc[mt][nt] = (f32x4){0.f, 0.f, 0.f, 0.f};

  for (int k0 = 0; k0 < HID; k0 += 64) {
#pragma unroll
    for (int it = 0; it < 4; it++) {
      int idx = it * 256 + tid;
      int row = idx >> 3, col8 = (idx & 7) * 8;
      *(uint4*)&As[row * 72 + col8] =
          *(const uint4*)&Hbf[(size_t)(i0 + row) * HID + k0 + col8];
      *(uint4*)&Bs[row * 72 + col8] =
          *(const uint4*)&Wpbf[(size_t)(n0 + row) * HID + k0 + col8];
    }
    __syncthreads();
#pragma unroll
    for (int ks = 0; ks < 2; ks++) {
      const int kk = ks * 32 + lkg * 8;
      bf16x8 a[4], b[4];
#pragma unroll
      for (int mt = 0; mt < 4; mt++)
        a[mt] = *(const bf16x8*)&As[(wm * 64 + mt * 16 + lrow) * 72 + kk];
#pragma unroll
      for (int nt = 0; nt < 4; nt++)
        b[nt] = *(const bf16x8*)&Bs[(wn * 64 + nt * 16 + lrow) * 72 + kk];
#pragma unroll
      for (int mt = 0; mt < 4; mt++)
#pragma unroll
        for (int nt = 0; nt < 4; nt++)
          acc[mt][nt] = __builtin_amdgcn_mfma_f32_16x16x32_bf16(
              a[mt], b[nt], acc[mt][nt], 0, 0, 0);
    }
    __syncthreads();
  }

  const float* bias = (seg == 0) ? bh : ((seg == 1) ? bm : bc);
  unsigned short* T = (seg == 0) ? HdT : MdT;
#pragma unroll
  for (int mt = 0; mt < 4; mt++)
#pragma unroll
    for (int nt = 0; nt < 4; nt++) {
      int nl = nloc0 + wn * 64 + nt * 16 + lrow;
      float bv = bias[nl];
      int mbase = i0 + wm * 64 + mt * 16 + lkg * 4;
      if (seg == 2) {
#pragma unroll
        for (int r = 0; r < 4; r++)
          Cu[(size_t)(mbase + r) * HID + nl] = acc[mt][nt][r] + bv;
      } else {
        unsigned v0 = (unsigned)f2bf(acc[mt][nt][0] + bv) |
                      ((unsigned)f2bf(acc[mt][nt][1] + bv) << 16);
        unsigned v1 = (unsigned)f2bf(acc[mt][nt][2] + bv) |
                      ((unsigned)f2bf(acc[mt][nt][3] + bv) << 16);
        uint2 pk; pk.x = v0; pk.y = v1;
        *(uint2*)&T[(size_t)nl * S_LEN + mbase] = pk;   // 8B aligned (mbase%4==0)
      }
    }
}

// ---------------------------------------------------------------------------
// MFMA GCN: Gbf[i][d] = bf16(tanh(Cu[i][d]
//            + sum_{j<i} dep[j][i]*Hd[j][d] + sum_{j<i} dep[i][j]*Md[j][d]))
// A1[i][j]=dep[j][i] masked (transposed staging); A2[i][j]=dep[i][j] masked;
// B from HdT/MdT [d][j] (row-major-K, vectorized). Both products -> one acc.
// ---------------------------------------------------------------------------
__global__ __launch_bounds__(256) void gcn_mfma_kernel(
    const float* __restrict__ dep,            // [4097][4097]
    const unsigned short* __restrict__ HdT,   // [1024][4096]
    const unsigned short* __restrict__ MdT,   // [1024][4096]
    const float* __restrict__ Cu,             // [4096][1024]
    unsigned short* __restrict__ Gbf)         // [4096][1024] bf16
{
  __shared__ unsigned short As1[128 * 72];
  __shared__ unsigned short As2[128 * 72];
  __shared__ unsigned short Bs1[128 * 72];
  __shared__ unsigned short Bs2[128 * 72];
  const int tid = threadIdx.x;
  const int lane = tid & 63;
  const int wid = tid >> 6;
  const int wm = wid >> 1, wn = wid & 1;
  const int lrow = lane & 15, lkg = lane >> 4;
  const int i0 = blockIdx.x * 128;
  const int d0 = blockIdx.y * 128;

  f32x4 acc[4][4];
#pragma unroll
  for (int mt = 0; mt < 4; mt++)
#pragma unroll
    for (int nt = 0; nt < 4; nt++) acc[mt][nt] = (f32x4){0.f, 0.f, 0.f, 0.f};

  const int jmax = i0 + 128;    // strict mask j<i kills everything beyond
  for (int j0 = 0; j0 < jmax; j0 += 64) {
    // heads A1[ii][jj] = (j<i) ? dep[j][i] : 0   (i-contig reads, transposed LDS)
    for (int e = tid; e < 128 * 64; e += 256) {
      int ii = e & 127, jj = e >> 7;
      int j = j0 + jj, i = i0 + ii;
      As1[ii * 72 + jj] = (j < i) ? f2bf(dep[(size_t)j * (S_LEN + 1) + i])
                                  : (unsigned short)0;
    }
    // mods A2[ii][jj] = (j<i) ? dep[i][j] : 0   (j-contig reads, direct LDS)
    for (int e = tid; e < 128 * 64; e += 256) {
      int jj = e & 63, ii = e >> 6;
      int j = j0 + jj, i = i0 + ii;
      As2[ii * 72 + jj] = (j < i) ? f2bf(dep[(size_t)i * (S_LEN + 1) + j])
                                  : (unsigned short)0;
    }
    // B tiles: [d][j] row-major-K, uint4 vectorized
    for (int e = tid; e < 128 * 8; e += 256) {
      int row = e >> 3, col8 = (e & 7) * 8;
      *(uint4*)&Bs1[row * 72 + col8] =
          *(const uint4*)&HdT[(size_t)(d0 + row) * S_LEN + j0 + col8];
      *(uint4*)&Bs2[row * 72 + col8] =
          *(const uint4*)&MdT[(size_t)(d0 + row) * S_LEN + j0 + col8];
    }
    __syncthreads();
#pragma unroll
    for (int ks = 0; ks < 2; ks++) {
      const int kk = ks * 32 + lkg * 8;
      bf16x8 a1[4], a2[4], b1[4], b2[4];
#pragma unroll
      for (int mt = 0; mt < 4; mt++) {
        a1[mt] = *(const bf16x8*)&As1[(wm * 64 + mt * 16 + lrow) * 72 + kk];
        a2[mt] = *(const bf16x8*)&As2[(wm * 64 + mt * 16 + lrow) * 72 + kk];
      }
#pragma unroll
      for (int nt = 0; nt < 4; nt++) {
        b1[nt] = *(const bf16x8*)&Bs1[(wn * 64 + nt * 16 + lrow) * 72 + kk];
        b2[nt] = *(const bf16x8*)&Bs2[(wn * 64 + nt * 16 + lrow) * 72 + kk];
      }
#pragma unroll
      for (int mt = 0; mt < 4; mt++)
#pragma unroll
        for (int nt = 0; nt < 4; nt++) {
          acc[mt][nt] = __builtin_amdgcn_mfma_f32_16x16x32_bf16(
              a1[mt], b1[nt], acc[mt][nt], 0, 0, 0);
          acc[mt][nt] = __builtin_amdgcn_mfma_f32_16x16x32_bf16(
              a2[mt], b2[nt], acc[mt][nt], 0, 0, 0);
        }
    }
    __syncthreads();
  }

#pragma unroll
  for (int mt = 0; mt < 4; mt++)
#pragma unroll
    for (int nt = 0; nt < 4; nt++) {
      int n = d0 + wn * 64 + nt * 16 + lrow;
#pragma unroll
      for (int r = 0; r < 4; r++) {
        int m = i0 + wm * 64 + mt * 16 + lkg * 4 + r;
        float vv = acc[mt][nt][r] + Cu[(size_t)m * HID + n];
        Gbf[(size_t)m * HID + n] = f2bf(tanhf(vv));
      }
    }
}

// ---------------------------------------------------------------------------
// MFMA bf16 fused vocab GEMM + online log-softmax partials. (validated)
// ---------------------------------------------------------------------------
__global__ __launch_bounds__(256) void loss_mfma_kernel(
    const unsigned short* __restrict__ Gbf,   // [4096][1024] bf16
    const unsigned short* __restrict__ Wobf,  // [32000][1024] bf16
    const float* __restrict__ bo, const int* __restrict__ tokens,
    float* __restrict__ pm, float* __restrict__ ps, float* __restrict__ pt)
{
  __shared__ unsigned short As[128 * 72];
  __shared__ unsigned short Bs[128 * 72];
  const int tid = threadIdx.x;
  const int lane = tid & 63;
  const int wid = tid >> 6;
  const int wm = wid >> 1;        // row half (0..1)
  const int wn = wid & 1;         // col half (0..1)
  const int lrow = lane & 15;
  const int lkg  = lane >> 4;     // 0..3
  const int i0 = blockIdx.x * 128;
  const int part = blockIdx.y;
  const int nbase = part * 1280;

  float rmax[4][4], rsum[4][4], tsum[4][4];
  int tg[4][4];
#pragma unroll
  for (int mt = 0; mt < 4; mt++)
#pragma unroll
    for (int r = 0; r < 4; r++) {
      rmax[mt][r] = -1e30f; rsum[mt][r] = 0.f; tsum[mt][r] = 0.f;
      tg[mt][r] = tokens[1 + i0 + wm * 64 + mt * 16 + lkg * 4 + r];
    }

  for (int c = 0; c < 10; c++) {
    const int n0 = nbase + c * 128;
    f32x4 acc[4][4];
#pragma unroll
    for (int mt = 0; mt < 4; mt++)
#pragma unroll
      for (int nt = 0; nt < 4; nt++) acc[mt][nt] = (f32x4){0.f, 0.f, 0.f, 0.f};

    for (int k0 = 0; k0 < HID; k0 += 64) {
#pragma unroll
      for (int it = 0; it < 4; it++) {
        int idx = it * 256 + tid;
        int row = idx >> 3, col8 = (idx & 7) * 8;
        *(uint4*)&As[row * 72 + col8] =
            *(const uint4*)&Gbf[(size_t)(i0 + row) * HID + k0 + col8];
        *(uint4*)&Bs[row * 72 + col8] =
            *(const uint4*)&Wobf[(size_t)(n0 + row) * HID + k0 + col8];
      }
      __syncthreads();
#pragma unroll
      for (int ks = 0; ks < 2; ks++) {
        const int kk = ks * 32 + lkg * 8;
        bf16x8 a[4], b[4];
#pragma unroll
        for (int mt = 0; mt < 4; mt++)
          a[mt] = *(const bf16x8*)&As[(wm * 64 + mt * 16 + lrow) * 72 + kk];
#pragma unroll
        for (int nt = 0; nt < 4; nt++)
          b[nt] = *(const bf16x8*)&Bs[(wn * 64 + nt * 16 + lrow) * 72 + kk];
#pragma unroll
        for (int mt = 0; mt < 4; mt++)
#pragma unroll
          for (int nt = 0; nt < 4; nt++)
            acc[mt][nt] = __builtin_amdgcn_mfma_f32_16x16x32_bf16(
                a[mt], b[nt], acc[mt][nt], 0, 0, 0);
      }
      __syncthreads();
    }

    float bov[4];
#pragma unroll
    for (int nt = 0; nt < 4; nt++)
      bov[nt] = bo[n0 + wn * 64 + nt * 16 + lrow];

#pragma unroll
    for (int mt = 0; mt < 4; mt++)
#pragma unroll
      for (int r = 0; r < 4; r++) {
        float v0 = acc[mt][0][r] + bov[0];
        float v1 = acc[mt][1][r] + bov[1];
        float v2 = acc[mt][2][r] + bov[2];
        float v3 = acc[mt][3][r] + bov[3];
        float cm = fmaxf(fmaxf(v0, v1), fmaxf(v2, v3));
#pragma unroll
        for (int off = 1; off < 16; off <<= 1) cm = fmaxf(cm, __shfl_xor(cm, off, 64));
        float nm = fmaxf(rmax[mt][r], cm);
        float sp = __expf(v0 - nm) + __expf(v1 - nm) + __expf(v2 - nm) + __expf(v3 - nm);
#pragma unroll
        for (int off = 1; off < 16; off <<= 1) sp += __shfl_xor(sp, off, 64);
        rsum[mt][r] = rsum[mt][r] * __expf(rmax[mt][r] - nm) + sp;
        rmax[mt][r] = nm;
        int nc = n0 + wn * 64 + lrow;
        if (nc       == tg[mt][r]) tsum[mt][r] += v0;
        if (nc + 16  == tg[mt][r]) tsum[mt][r] += v1;
        if (nc + 32  == tg[mt][r]) tsum[mt][r] += v2;
        if (nc + 48  == tg[mt][r]) tsum[mt][r] += v3;
      }
  }

  const int p = part * 2 + wn;
#pragma unroll
  for (int mt = 0; mt < 4; mt++)
#pragma unroll
    for (int r = 0; r < 4; r++) {
      float tv = tsum[mt][r];
#pragma unroll
      for (int off = 1; off < 16; off <<= 1) tv += __shfl_xor(tv, off, 64);
      if (lrow == 0) {
        int m = i0 + wm * 64 + mt * 16 + lkg * 4 + r;
        pm[p * S_LEN + m] = rmax[mt][r];
        ps[p * S_LEN + m] = rsum[mt][r];
        pt[p * S_LEN + m] = tv;
      }
    }
}

// ---------------------------------------------------------------------------
// Combine partials across the NPCOL column-partials -> mean NLL
// ---------------------------------------------------------------------------
__global__ __launch_bounds__(256) void combine_kernel(
    const float* __restrict__ pm, const float* __restrict__ ps,
    const float* __restrict__ pt, float* __restrict__ out)
{
  const int tid = threadIdx.x;
  float lsum = 0.f;
  for (int r = tid; r < S_LEN; r += 256) {
    float M = -1e30f;
    for (int p = 0; p < NPCOL; p++) M = fmaxf(M, pm[p * S_LEN + r]);
    float S = 0.f, tv = 0.f;
    for (int p = 0; p < NPCOL; p++) {
      S += ps[p * S_LEN + r] * expf(pm[p * S_LEN + r] - M);
      tv += pt[p * S_LEN + r];
    }
    lsum += (M + logf(S)) - tv;
  }
  __shared__ float red[256];
  red[tid] = lsum;
  __syncthreads();
  for (int s = 128; s > 0; s >>= 1) {
    if (tid < s) red[tid] += red[tid + s];
    __syncthreads();
  }
  if (tid == 0) out[0] = red[0] / (float)S_LEN;
}

// ---------------------------------------------------------------------------
extern "C" void kernel_launch(void* const* d_in, const int* in_sizes, int n_in,
                              void* d_out, int out_size, void* d_ws, size_t ws_size,
                              hipStream_t stream)
{
  const float* dep = (const float*)d_in[0];
  const float* emb = (const float*)d_in[1];
  const float* Wih = (const float*)d_in[2];
  const float* Whh = (const float*)d_in[3];
  const float* bih = (const float*)d_in[4];
  const float* bhh = (const float*)d_in[5];
  const float* Wh  = (const float*)d_in[6];
  const float* bh  = (const float*)d_in[7];
  const float* Wm  = (const float*)d_in[8];
  const float* bm  = (const float*)d_in[9];
  const float* Wc  = (const float*)d_in[10];
  const float* bc  = (const float*)d_in[11];
  const float* Wo  = (const float*)d_in[12];
  const float* bo  = (const float*)d_in[13];
  const int*   tok = (const int*)d_in[14];
  float* out = (float*)d_out;

  float* ws = (float*)d_ws;
  size_t o = 0;
  float* Gx = ws + o; o += (size_t)S_LEN * G4H;    // 67 MB; dead after lstm
  float* Hs = ws + o; o += (size_t)S_LEN * HID;
  float* Cu = ws + o; o += (size_t)S_LEN * HID;
  float* pm = ws + o; o += (size_t)NPCOL * S_LEN;
  float* ps_ = ws + o; o += (size_t)NPCOL * S_LEN;
  float* pt_ = ws + o; o += (size_t)NPCOL * S_LEN;
  unsigned short* Gbf = (unsigned short*)(ws + o); o += (size_t)S_LEN * HID / 2;
  unsigned short* Hbf = (unsigned short*)(ws + o); o += (size_t)S_LEN * HID / 2;
  unsigned short* HdT = (unsigned short*)(ws + o); o += (size_t)S_LEN * HID / 2;
  unsigned short* MdT = (unsigned short*)(ws + o); o += (size_t)S_LEN * HID / 2;
  unsigned short* Wpbf = (unsigned short*)(ws + o); o += (size_t)3 * HID * HID / 2;
  int* flags = (int*)(ws + o);
  // Wobf aliases Gx (65.5 MB <= 67 MB), written only after lstm_kernel finished
  unsigned short* Wobf = (unsigned short*)Gx;

  hipMemsetAsync(flags, 0, NWG_LSTM * FLAG_STRIDE * sizeof(int), stream);

  dim3 blk(256);
  // Gx = emb[tok] @ W_ih^T + b_ih + b_hh
  gemm_abt<128, 128, 16, 8, 8, true, true><<<dim3(32, 32), blk, 0, stream>>>(
      emb, EDIM, tok, Wih, EDIM, bih, bhh, Gx, G4H, EDIM);

  // sequential LSTM — cooperative launch, 128 WGs x 256 threads (r12 config)
  {
    void* args[] = {(void*)&Gx, (void*)&Whh, (void*)&Hs, (void*)&flags};
    hipLaunchCooperativeKernel((const void*)lstm_kernel, dim3(NWG_LSTM),
                               dim3(256), args, 0, stream);
  }

  // conversions
  conv_bf16_kernel<<<dim3(2048), blk, 0, stream>>>(Wo, Wobf, VOC * HID / 8);
  conv_bf16_kernel<<<dim3(512), blk, 0, stream>>>(Hs, Hbf, S_LEN * HID / 8);
  conv_bf16_kernel<<<dim3(512), blk, 0, stream>>>(Wh, Wpbf, HID * HID / 8);
  conv_bf16_kernel<<<dim3(512), blk, 0, stream>>>(Wm, Wpbf + (size_t)HID * HID, HID * HID / 8);
  conv_bf16_kernel<<<dim3(512), blk, 0, stream>>>(Wc, Wpbf + (size_t)2 * HID * HID, HID * HID / 8);

  // projections (MFMA): HdT/MdT bf16 transposed + Cu fp32
  proj_mfma_kernel<<<dim3(32, 24), blk, 0, stream>>>(
      Hbf, Wpbf, bh, bm, bc, HdT, MdT, Cu);
  // GCN (MFMA) + tanh -> Gbf (bf16)
  gcn_mfma_kernel<<<dim3(32, 8), blk, 0, stream>>>(dep, HdT, MdT, Cu, Gbf);
  // fused MFMA vocab GEMM + online log-softmax partials
  loss_mfma_kernel<<<dim3(32, NPART), blk, 0, stream>>>(
      Gbf, Wobf, bo, tok, pm, ps_, pt_);
  // combine -> scalar loss
  combine_kernel<<<dim3(1), blk, 0, stream>>>(pm, ps_, pt_, out);
}

// Round 16
// 20087.956 us; speedup vs baseline: 1.5821x; 1.2649x over previous
//
#include <hip/hip_runtime.h>
#include <hip/hip_bf16.h>
#include <math.h>

#define S_LEN 4096
#define HID   1024
#define G4H   4096
#define EDIM  300
#define VOC   32000
#define NWG_LSTM 128
#define HPW   8           // h units per workgroup
#define NPART 25          // vocab parts for loss kernel (25 * 1280 = 32000)
#define NPCOL 50          // partial columns = NPART * 2 wave-halves

typedef __attribute__((ext_vector_type(8))) short bf16x8;
typedef __attribute__((ext_vector_type(4))) float f32x4;

__device__ __forceinline__ float bf_lo(unsigned u){ return __uint_as_float(u << 16); }
__device__ __forceinline__ float bf_hi(unsigned u){ return __uint_as_float(u & 0xffff0000u); }
__device__ __forceinline__ unsigned short f2bf(float x){
  unsigned u = __float_as_uint(x);
  unsigned r = (u + 0x7fffu + ((u >> 16) & 1u)) >> 16;
  return (unsigned short)r;
}

// ---------------------------------------------------------------------------
// fp32 -> bf16 conversion, 8 elems/thread
// ---------------------------------------------------------------------------
__global__ __launch_bounds__(256) void conv_bf16_kernel(
    const float* __restrict__ in, unsigned short* __restrict__ out, int n8)
{
  for (int i = blockIdx.x * blockDim.x + threadIdx.x; i < n8;
       i += gridDim.x * blockDim.x) {
    const float4* p = (const float4*)(in + (size_t)i * 8);
    float4 a = p[0], b = p[1];
    uint4 o;
    o.x = (unsigned)f2bf(a.x) | ((unsigned)f2bf(a.y) << 16);
    o.y = (unsigned)f2bf(a.z) | ((unsigned)f2bf(a.w) << 16);
    o.z = (unsigned)f2bf(b.x) | ((unsigned)f2bf(b.y) << 16);
    o.w = (unsigned)f2bf(b.z) | ((unsigned)f2bf(b.w) << 16);
    *(uint4*)(out + (size_t)i * 8) = o;
  }
}

// tagged-u64 h -> bf16 (low 32 bits hold the f32)
__global__ __launch_bounds__(256) void conv_h_bf16_kernel(
    const unsigned long long* __restrict__ in, unsigned short* __restrict__ out,
    int n8)
{
  for (int i = blockIdx.x * blockDim.x + threadIdx.x; i < n8;
       i += gridDim.x * blockDim.x) {
    const ulonglong2* p = (const ulonglong2*)(in + (size_t)i * 8);
    ulonglong2 q0 = p[0], q1 = p[1], q2 = p[2], q3 = p[3];
    uint4 o;
    o.x = (unsigned)f2bf(__uint_as_float((unsigned)q0.x)) |
          ((unsigned)f2bf(__uint_as_float((unsigned)q0.y)) << 16);
    o.y = (unsigned)f2bf(__uint_as_float((unsigned)q1.x)) |
          ((unsigned)f2bf(__uint_as_float((unsigned)q1.y)) << 16);
    o.z = (unsigned)f2bf(__uint_as_float((unsigned)q2.x)) |
          ((unsigned)f2bf(__uint_as_float((unsigned)q2.y)) << 16);
    o.w = (unsigned)f2bf(__uint_as_float((unsigned)q3.x)) |
          ((unsigned)f2bf(__uint_as_float((unsigned)q3.y)) << 16);
    *(uint4*)(out + (size_t)i * 8) = o;
  }
}

// ---------------------------------------------------------------------------
// Generic C = A @ B^T + bias1 (+bias2), A rows optionally gathered. (Gx only)
// ---------------------------------------------------------------------------
template<int BM, int BN, int BK, int TM, int TN, bool GATHER, bool HASB2>
__global__ __launch_bounds__(256) void gemm_abt(
    const float* __restrict__ A, int lda, const int* __restrict__ gidx,
    const float* __restrict__ B, int ldb,
    const float* __restrict__ bias1, const float* __restrict__ bias2,
    float* __restrict__ C, int ldc, int K)
{
  __shared__ float As[BK][BM + 1];
  __shared__ float Bs[BK][BN + 1];
  const int tid = threadIdx.x;
  const int tx = tid & 15, ty = tid >> 4;
  const int m0 = blockIdx.x * BM, n0 = blockIdx.y * BN;

  float acc[TM][TN];
#pragma unroll
  for (int i = 0; i < TM; i++)
#pragma unroll
    for (int j = 0; j < TN; j++) acc[i][j] = 0.f;

  for (int k0 = 0; k0 < K; k0 += BK) {
    for (int e = tid; e < BM * BK; e += 256) {
      int kk = e & (BK - 1); int m = e / BK;
      int k = k0 + kk;
      int row = GATHER ? gidx[m0 + m] : (m0 + m);
      As[kk][m] = (k < K) ? A[(size_t)row * lda + k] : 0.f;
    }
    for (int e = tid; e < BN * BK; e += 256) {
      int kk = e & (BK - 1); int n = e / BK;
      int k = k0 + kk;
      Bs[kk][n] = (k < K) ? B[(size_t)(n0 + n) * ldb + k] : 0.f;
    }
    __syncthreads();
#pragma unroll
    for (int kk = 0; kk < BK; kk++) {
      float a[TM], b[TN];
#pragma unroll
      for (int i = 0; i < TM; i++) a[i] = As[kk][ty + i * 16];
#pragma unroll
      for (int j = 0; j < TN; j++) b[j] = Bs[kk][tx + j * 16];
#pragma unroll
      for (int i = 0; i < TM; i++)
#pragma unroll
        for (int j = 0; j < TN; j++) acc[i][j] = fmaf(a[i], b[j], acc[i][j]);
    }
    __syncthreads();
  }
#pragma unroll
  for (int i = 0; i < TM; i++)
#pragma unroll
    for (int j = 0; j < TN; j++) {
      int m = m0 + ty + i * 16, n = n0 + tx + j * 16;
      float v = acc[i][j] + bias1[n];
      if (HASB2) v += bias2[n];
      C[(size_t)m * ldc + n] = v;
    }
}

// ---------------------------------------------------------------------------
// Persistent LSTM scan, cooperative launch. 128 WGs x 256 threads.
// TAGGED-H protocol (r16): h published as u64 {tag=t+1 | f32(h)} via relaxed
// agent-scope atomic stores. Consumers POLL THE DATA ITSELF: 16 coalesced
// u64 atomic loads/lane/round until all 1024 tags == t. Detect==gather: when
// the poll exits, h is already in registers. No flags, no RELEASE, no drain.
// Hs2 tags are zeroed by hipMemsetAsync each launch (no cross-call state).
// gsum reuse safe: wave passes t+1 poll only after own finisher (who read
// gsum at t) published its tags.
// ---------------------------------------------------------------------------
__global__ __launch_bounds__(256) void lstm_kernel(
    const float* __restrict__ Gx,          // [4096][4096] x-part + both biases
    const float* __restrict__ Whh,         // [4096][1024]
    unsigned long long* __restrict__ Hs2)  // [4096][1024] tagged h, zeroed
{
  const int wg = blockIdx.x;
  const int tid = threadIdx.x;
  const int v = tid >> 6;       // wave id == gate id (0:i 1:f 2:g 3:o)
  const int lane = tid & 63;

  __shared__ float gsum[4][HPW];

  // weight pack matched to tagged-h layout: lane owns h[i*64 + lane], i=0..15
  // wreg[r*8+j] packs (W[row][2j*64+lane], W[row][(2j+1)*64+lane])
  unsigned wreg[64];
  {
#pragma unroll
    for (int r = 0; r < 8; r++) {
      int row = v * HID + wg * HPW + r;
#pragma unroll
      for (int j = 0; j < 8; j++) {
        float w0 = Whh[(size_t)row * HID + (2 * j) * 64 + lane];
        float w1 = Whh[(size_t)row * HID + (2 * j + 1) * 64 + lane];
        wreg[r * 8 + j] = ((unsigned)f2bf(w1) << 16) | (unsigned)f2bf(w0);
      }
    }
  }
  float creg = 0.f;   // c-state, lanes<8 of wave 0 only

  for (int t = 0; t < S_LEN; t++) {
    // prefetch Gx for finishers (normal cached loads, in flight during poll)
    float gx0 = 0.f, gx1 = 0.f, gx2 = 0.f, gx3 = 0.f;
    if (tid < HPW) {
      size_t b = (size_t)t * G4H + wg * HPW + tid;
      gx0 = Gx[b];
      gx1 = Gx[b + 1024];
      gx2 = Gx[b + 2048];
      gx3 = Gx[b + 3072];
    }

    float hv[16];
    if (t > 0) {
      const unsigned long long* hp = Hs2 + (size_t)(t - 1) * HID;
      unsigned long long hv64[16];
      while (true) {
        bool ok = true;
#pragma unroll
        for (int i = 0; i < 16; i++) {
          hv64[i] = __hip_atomic_load(&hp[i * 64 + lane], __ATOMIC_RELAXED,
                                      __HIP_MEMORY_SCOPE_AGENT);
          ok &= ((unsigned)(hv64[i] >> 32) == (unsigned)t);
        }
        if (__all(ok)) break;
        __builtin_amdgcn_s_sleep(1);
      }
      asm volatile("" ::: "memory");
#pragma unroll
      for (int i = 0; i < 16; i++) hv[i] = __uint_as_float((unsigned)hv64[i]);
    } else {
#pragma unroll
      for (int i = 0; i < 16; i++) hv[i] = 0.f;
    }

#pragma unroll
    for (int r = 0; r < 8; r++) {
      float acc = 0.f;
#pragma unroll
      for (int j = 0; j < 8; j++) {
        unsigned w = wreg[r * 8 + j];
        acc = fmaf(bf_lo(w), hv[2 * j], acc);
        acc = fmaf(bf_hi(w), hv[2 * j + 1], acc);
      }
#pragma unroll
      for (int off = 1; off < 64; off <<= 1) acc += __shfl_xor(acc, off, 64);
      if (lane == 0) gsum[v][r] = acc;
    }
    __syncthreads();

    if (tid < HPW) {
      const int hu = tid;
      float gi = gsum[0][hu] + gx0;
      float gf = gsum[1][hu] + gx1;
      float gg = gsum[2][hu] + gx2;
      float go = gsum[3][hu] + gx3;
      float i_ = 1.f / (1.f + expf(-gi));
      float f_ = 1.f / (1.f + expf(-gf));
      float g_ = tanhf(gg);
      float o_ = 1.f / (1.f + expf(-go));
      float c = f_ * creg + i_ * g_;
      creg = c;
      float h = o_ * tanhf(c);
      unsigned long long pkt = (unsigned long long)__float_as_uint(h) |
                               ((unsigned long long)(unsigned)(t + 1) << 32);
      __hip_atomic_store(&Hs2[(size_t)t * HID + wg * HPW + hu], pkt,
                         __ATOMIC_RELAXED, __HIP_MEMORY_SCOPE_AGENT);
    }
    // no flag, no drain: the tagged stores ARE the release
  }
}

// ---------------------------------------------------------------------------
// MFMA projections: C[m][n] = Hbf[m][:] . Wpbf[n][:], m=seq 4096, n=0..3071
// ---------------------------------------------------------------------------
__global__ __launch_bounds__(256) void proj_mfma_kernel(
    const unsigned short* __restrict__ Hbf,   // [4096][1024]
    const unsigned short* __restrict__ Wpbf,  // [3072][1024]
    const float* __restrict__ bh, const float* __restrict__ bm,
    const float* __restrict__ bc,
    unsigned short* __restrict__ HdT,         // [1024][4096] bf16
    unsigned short* __restrict__ MdT,         // [1024][4096] bf16
    float* __restrict__ Cu)                   // [4096][1024] fp32
{
  __shared__ unsigned short As[128 * 72];
  __shared__ unsigned short Bs[128 * 72];
  const int tid = threadIdx.x;
  const int lane = tid & 63;
  const int wid = tid >> 6;
  const int wm = wid >> 1, wn = wid & 1;
  const int lrow = lane & 15, lkg = lane >> 4;
  const int i0 = blockIdx.x * 128;
  const int nb = blockIdx.y;            // 0..23
  const int n0 = nb * 128;              // row into Wpbf
  const int seg = nb >> 3;              // 0:Wh 1:Wm 2:Wc
  const int nloc0 = (nb & 7) * 128;     // col base within segment

  f32x4 acc[4][4];
#pragma unroll
  for (int mt = 0; mt < 4; mt++)
#pragma unroll
    for (int nt = 0; nt < 4; nt++) acc[mt][nt] = (f32x4){0.f, 0.f, 0.f, 0.f};

  for (int k0 = 0; k0 < HID; k0 += 64) {
#pragma unroll
    for (int it = 0; it < 4; it++) {
      int idx = it * 256 + tid;
      int row = idx >> 3, col8 = (idx & 7) * 8;
      *(uint4*)&As[row * 72 + col8] =
          *(const uint4*)&Hbf[(size_t)(i0 + row) * HID + k0 + col8];
      *(uint4*)&Bs[row * 72 + col8] =
          *(const uint4*)&Wpbf[(size_t)(n0 + row) * HID + k0 + col8];
    }
    __syncthreads();
#pragma unroll
    for (int ks = 0; ks < 2; ks++) {
      const int kk = ks * 32 + lkg * 8;
      bf16x8 a[4], b[4];
#pragma unroll
      for (int mt = 0; mt < 4; mt++)
        a[mt] = *(const bf16x8*)&As[(wm * 64 + mt * 16 + lrow) * 72 + kk];
#pragma unroll
      for (int nt = 0; nt < 4; nt++)
        b[nt] = *(const bf16x8*)&Bs[(wn * 64 + nt * 16 + lrow) * 72 + kk];
#pragma unroll
      for (int mt = 0; mt < 4; mt++)
#pragma unroll
        for (int nt = 0; nt < 4; nt++)
          acc[mt][nt] = __builtin_amdgcn_mfma_f32_16x16x32_bf16(
              a[mt], b[nt], acc[mt][nt], 0, 0, 0);
    }
    __syncthreads();
  }

  const float* bias = (seg == 0) ? bh : ((seg == 1) ? bm : bc);
  unsigned short* T = (seg == 0) ? HdT : MdT;
#pragma unroll
  for (int mt = 0; mt < 4; mt++)
#pragma unroll
    for (int nt = 0; nt < 4; nt++) {
      int nl = nloc0 + wn * 64 + nt * 16 + lrow;
      float bv = bias[nl];
      int mbase = i0 + wm * 64 + mt * 16 + lkg * 4;
      if (seg == 2) {
#pragma unroll
        for (int r = 0; r < 4; r++)
          Cu[(size_t)(mbase + r) * HID + nl] = acc[mt][nt][r] + bv;
      } else {
        unsigned v0 = (unsigned)f2bf(acc[mt][nt][0] + bv) |
                      ((unsigned)f2bf(acc[mt][nt][1] + bv) << 16);
        unsigned v1 = (unsigned)f2bf(acc[mt][nt][2] + bv) |
                      ((unsigned)f2bf(acc[mt][nt][3] + bv) << 16);
        uint2 pk; pk.x = v0; pk.y = v1;
        *(uint2*)&T[(size_t)nl * S_LEN + mbase] = pk;
      }
    }
}

// ---------------------------------------------------------------------------
// MFMA GCN: Gbf[i][d] = bf16(tanh(Cu[i][d]
//            + sum_{j<i} dep[j][i]*Hd[j][d] + sum_{j<i} dep[i][j]*Md[j][d]))
// ---------------------------------------------------------------------------
__global__ __launch_bounds__(256) void gcn_mfma_kernel(
    const float* __restrict__ dep,            // [4097][4097]
    const unsigned short* __restrict__ HdT,   // [1024][4096]
    const unsigned short* __restrict__ MdT,   // [1024][4096]
    const float* __restrict__ Cu,             // [4096][1024]
    unsigned short* __restrict__ Gbf)         // [4096][1024] bf16
{
  __shared__ unsigned short As1[128 * 72];
  __shared__ unsigned short As2[128 * 72];
  __shared__ unsigned short Bs1[128 * 72];
  __shared__ unsigned short Bs2[128 * 72];
  const int tid = threadIdx.x;
  const int lane = tid & 63;
  const int wid = tid >> 6;
  const int wm = wid >> 1, wn = wid & 1;
  const int lrow = lane & 15, lkg = lane >> 4;
  const int i0 = blockIdx.x * 128;
  const int d0 = blockIdx.y * 128;

  f32x4 acc[4][4];
#pragma unroll
  for (int mt = 0; mt < 4; mt++)
#pragma unroll
    for (int nt = 0; nt < 4; nt++) acc[mt][nt] = (f32x4){0.f, 0.f, 0.f, 0.f};

  const int jmax = i0 + 128;
  for (int j0 = 0; j0 < jmax; j0 += 64) {
    for (int e = tid; e < 128 * 64; e += 256) {
      int ii = e & 127, jj = e >> 7;
      int j = j0 + jj, i = i0 + ii;
      As1[ii * 72 + jj] = (j < i) ? f2bf(dep[(size_t)j * (S_LEN + 1) + i])
                                  : (unsigned short)0;
    }
    for (int e = tid; e < 128 * 64; e += 256) {
      int jj = e & 63, ii = e >> 6;
      int j = j0 + jj, i = i0 + ii;
      As2[ii * 72 + jj] = (j < i) ? f2bf(dep[(size_t)i * (S_LEN + 1) + j])
                                  : (unsigned short)0;
    }
    for (int e = tid; e < 128 * 8; e += 256) {
      int row = e >> 3, col8 = (e & 7) * 8;
      *(uint4*)&Bs1[row * 72 + col8] =
          *(const uint4*)&HdT[(size_t)(d0 + row) * S_LEN + j0 + col8];
      *(uint4*)&Bs2[row * 72 + col8] =
          *(const uint4*)&MdT[(size_t)(d0 + row) * S_LEN + j0 + col8];
    }
    __syncthreads();
#pragma unroll
    for (int ks = 0; ks < 2; ks++) {
      const int kk = ks * 32 + lkg * 8;
      bf16x8 a1[4], a2[4], b1[4], b2[4];
#pragma unroll
      for (int mt = 0; mt < 4; mt++) {
        a1[mt] = *(const bf16x8*)&As1[(wm * 64 + mt * 16 + lrow) * 72 + kk];
        a2[mt] = *(const bf16x8*)&As2[(wm * 64 + mt * 16 + lrow) * 72 + kk];
      }
#pragma unroll
      for (int nt = 0; nt < 4; nt++) {
        b1[nt] = *(const bf16x8*)&Bs1[(wn * 64 + nt * 16 + lrow) * 72 + kk];
        b2[nt] = *(const bf16x8*)&Bs2[(wn * 64 + nt * 16 + lrow) * 72 + kk];
      }
#pragma unroll
      for (int mt = 0; mt < 4; mt++)
#pragma unroll
        for (int nt = 0; nt < 4; nt++) {
          acc[mt][nt] = __builtin_amdgcn_mfma_f32_16x16x32_bf16(
              a1[mt], b1[nt], acc[mt][nt], 0, 0, 0);
          acc[mt][nt] = __builtin_amdgcn_mfma_f32_16x16x32_bf16(
              a2[mt], b2[nt], acc[mt][nt], 0, 0, 0);
        }
    }
    __syncthreads();
  }

#pragma unroll
  for (int mt = 0; mt < 4; mt++)
#pragma unroll
    for (int nt = 0; nt < 4; nt++) {
      int n = d0 + wn * 64 + nt * 16 + lrow;
#pragma unroll
      for (int r = 0; r < 4; r++) {
        int m = i0 + wm * 64 + mt * 16 + lkg * 4 + r;
        float vv = acc[mt][nt][r] + Cu[(size_t)m * HID + n];
        Gbf[(size_t)m * HID + n] = f2bf(tanhf(vv));
      }
    }
}

// ---------------------------------------------------------------------------
// MFMA bf16 fused vocab GEMM + online log-softmax partials. (validated)
// ---------------------------------------------------------------------------
__global__ __launch_bounds__(256) void loss_mfma_kernel(
    const unsigned short* __restrict__ Gbf,   // [4096][1024] bf16
    const unsigned short* __restrict__ Wobf,  // [32000][1024] bf16
    const float* __restrict__ bo, const int* __restrict__ tokens,
    float* __restrict__ pm, float* __restrict__ ps, float* __restrict__ pt)
{
  __shared__ unsigned short As[128 * 72];
  __shared__ unsigned short Bs[128 * 72];
  const int tid = threadIdx.x;
  const int lane = tid & 63;
  const int wid = tid >> 6;
  const int wm = wid >> 1;
  const int wn = wid & 1;
  const int lrow = lane & 15;
  const int lkg  = lane >> 4;
  const int i0 = blockIdx.x * 128;
  const int part = blockIdx.y;
  const int nbase = part * 1280;

  float rmax[4][4], rsum[4][4], tsum[4][4];
  int tg[4][4];
#pragma unroll
  for (int mt = 0; mt < 4; mt++)
#pragma unroll
    for (int r = 0; r < 4; r++) {
      rmax[mt][r] = -1e30f; rsum[mt][r] = 0.f; tsum[mt][r] = 0.f;
      tg[mt][r] = tokens[1 + i0 + wm * 64 + mt * 16 + lkg * 4 + r];
    }

  for (int c = 0; c < 10; c++) {
    const int n0 = nbase + c * 128;
    f32x4 acc[4][4];
#pragma unroll
    for (int mt = 0; mt < 4; mt++)
#pragma unroll
      for (int nt = 0; nt < 4; nt++) acc[mt][nt] = (f32x4){0.f, 0.f, 0.f, 0.f};

    for (int k0 = 0; k0 < HID; k0 += 64) {
#pragma unroll
      for (int it = 0; it < 4; it++) {
        int idx = it * 256 + tid;
        int row = idx >> 3, col8 = (idx & 7) * 8;
        *(uint4*)&As[row * 72 + col8] =
            *(const uint4*)&Gbf[(size_t)(i0 + row) * HID + k0 + col8];
        *(uint4*)&Bs[row * 72 + col8] =
            *(const uint4*)&Wobf[(size_t)(n0 + row) * HID + k0 + col8];
      }
      __syncthreads();
#pragma unroll
      for (int ks = 0; ks < 2; ks++) {
        const int kk = ks * 32 + lkg * 8;
        bf16x8 a[4], b[4];
#pragma unroll
        for (int mt = 0; mt < 4; mt++)
          a[mt] = *(const bf16x8*)&As[(wm * 64 + mt * 16 + lrow) * 72 + kk];
#pragma unroll
        for (int nt = 0; nt < 4; nt++)
          b[nt] = *(const bf16x8*)&Bs[(wn * 64 + nt * 16 + lrow) * 72 + kk];
#pragma unroll
        for (int mt = 0; mt < 4; mt++)
#pragma unroll
          for (int nt = 0; nt < 4; nt++)
            acc[mt][nt] = __builtin_amdgcn_mfma_f32_16x16x32_bf16(
                a[mt], b[nt], acc[mt][nt], 0, 0, 0);
      }
      __syncthreads();
    }

    float bov[4];
#pragma unroll
    for (int nt = 0; nt < 4; nt++)
      bov[nt] = bo[n0 + wn * 64 + nt * 16 + lrow];

#pragma unroll
    for (int mt = 0; mt < 4; mt++)
#pragma unroll
      for (int r = 0; r < 4; r++) {
        float v0 = acc[mt][0][r] + bov[0];
        float v1 = acc[mt][1][r] + bov[1];
        float v2 = acc[mt][2][r] + bov[2];
        float v3 = acc[mt][3][r] + bov[3];
        float cm = fmaxf(fmaxf(v0, v1), fmaxf(v2, v3));
#pragma unroll
        for (int off = 1; off < 16; off <<= 1) cm = fmaxf(cm, __shfl_xor(cm, off, 64));
        float nm = fmaxf(rmax[mt][r], cm);
        float sp = __expf(v0 - nm) + __expf(v1 - nm) + __expf(v2 - nm) + __expf(v3 - nm);
#pragma unroll
        for (int off = 1; off < 16; off <<= 1) sp += __shfl_xor(sp, off, 64);
        rsum[mt][r] = rsum[mt][r] * __expf(rmax[mt][r] - nm) + sp;
        rmax[mt][r] = nm;
        int nc = n0 + wn * 64 + lrow;
        if (nc       == tg[mt][r]) tsum[mt][r] += v0;
        if (nc + 16  == tg[mt][r]) tsum[mt][r] += v1;
        if (nc + 32  == tg[mt][r]) tsum[mt][r] += v2;
        if (nc + 48  == tg[mt][r]) tsum[mt][r] += v3;
      }
  }

  const int p = part * 2 + wn;
#pragma unroll
  for (int mt = 0; mt < 4; mt++)
#pragma unroll
    for (int r = 0; r < 4; r++) {
      float tv = tsum[mt][r];
#pragma unroll
      for (int off = 1; off < 16; off <<= 1) tv += __shfl_xor(tv, off, 64);
      if (lrow == 0) {
        int m = i0 + wm * 64 + mt * 16 + lkg * 4 + r;
        pm[p * S_LEN + m] = rmax[mt][r];
        ps[p * S_LEN + m] = rsum[mt][r];
        pt[p * S_LEN + m] = tv;
      }
    }
}

// ---------------------------------------------------------------------------
// Combine partials across the NPCOL column-partials -> mean NLL
// ---------------------------------------------------------------------------
__global__ __launch_bounds__(256) void combine_kernel(
    const float* __restrict__ pm, const float* __restrict__ ps,
    const float* __restrict__ pt, float* __restrict__ out)
{
  const int tid = threadIdx.x;
  float lsum = 0.f;
  for (int r = tid; r < S_LEN; r += 256) {
    float M = -1e30f;
    for (int p = 0; p < NPCOL; p++) M = fmaxf(M, pm[p * S_LEN + r]);
    float S = 0.f, tv = 0.f;
    for (int p = 0; p < NPCOL; p++) {
      S += ps[p * S_LEN + r] * expf(pm[p * S_LEN + r] - M);
      tv += pt[p * S_LEN + r];
    }
    lsum += (M + logf(S)) - tv;
  }
  __shared__ float red[256];
  red[tid] = lsum;
  __syncthreads();
  for (int s = 128; s > 0; s >>= 1) {
    if (tid < s) red[tid] += red[tid + s];
    __syncthreads();
  }
  if (tid == 0) out[0] = red[0] / (float)S_LEN;
}

// ---------------------------------------------------------------------------
extern "C" void kernel_launch(void* const* d_in, const int* in_sizes, int n_in,
                              void* d_out, int out_size, void* d_ws, size_t ws_size,
                              hipStream_t stream)
{
  const float* dep = (const float*)d_in[0];
  const float* emb = (const float*)d_in[1];
  const float* Wih = (const float*)d_in[2];
  const float* Whh = (const float*)d_in[3];
  const float* bih = (const float*)d_in[4];
  const float* bhh = (const float*)d_in[5];
  const float* Wh  = (const float*)d_in[6];
  const float* bh  = (const float*)d_in[7];
  const float* Wm  = (const float*)d_in[8];
  const float* bm  = (const float*)d_in[9];
  const float* Wc  = (const float*)d_in[10];
  const float* bc  = (const float*)d_in[11];
  const float* Wo  = (const float*)d_in[12];
  const float* bo  = (const float*)d_in[13];
  const int*   tok = (const int*)d_in[14];
  float* out = (float*)d_out;

  float* ws = (float*)d_ws;
  size_t o = 0;
  float* Gx = ws + o; o += (size_t)S_LEN * G4H;              // 67 MB; Wobf alias
  unsigned long long* Hs2 = (unsigned long long*)(ws + o);   // 32 MB tagged h
  float* aliasBase = ws + o; o += (size_t)S_LEN * HID * 2;
  float* Cu = ws + o; o += (size_t)S_LEN * HID;
  float* pm = ws + o; o += (size_t)NPCOL * S_LEN;
  float* ps_ = ws + o; o += (size_t)NPCOL * S_LEN;
  float* pt_ = ws + o; o += (size_t)NPCOL * S_LEN;
  unsigned short* Hbf = (unsigned short*)(ws + o); o += (size_t)S_LEN * HID / 2;
  // buffers that alias Hs2 AFTER it is dead (post Hbf-extraction):
  unsigned short* Wpbf = (unsigned short*)aliasBase;                       // 6.3 MB
  unsigned short* HdT  = (unsigned short*)(aliasBase + (size_t)3 * HID * HID / 2);
  unsigned short* MdT  = HdT + (size_t)S_LEN * HID;
  unsigned short* Gbf  = MdT + (size_t)S_LEN * HID;                        // ends 31.5 MB
  // Wobf aliases Gx (65.5 MB <= 67 MB), written only after lstm_kernel finished
  unsigned short* Wobf = (unsigned short*)Gx;

  // zero the tagged-h buffer each launch: tags must start != any t in [1,4096]
  hipMemsetAsync(Hs2, 0, (size_t)S_LEN * HID * 8, stream);

  dim3 blk(256);
  // Gx = emb[tok] @ W_ih^T + b_ih + b_hh
  gemm_abt<128, 128, 16, 8, 8, true, true><<<dim3(32, 32), blk, 0, stream>>>(
      emb, EDIM, tok, Wih, EDIM, bih, bhh, Gx, G4H, EDIM);

  // sequential LSTM — cooperative launch, tagged-h protocol
  {
    void* args[] = {(void*)&Gx, (void*)&Whh, (void*)&Hs2};
    hipLaunchCooperativeKernel((const void*)lstm_kernel, dim3(NWG_LSTM),
                               dim3(256), args, 0, stream);
  }

  // conversions (order matters: Hbf from Hs2 BEFORE anything aliases Hs2)
  conv_h_bf16_kernel<<<dim3(512), blk, 0, stream>>>(Hs2, Hbf, S_LEN * HID / 8);
  conv_bf16_kernel<<<dim3(2048), blk, 0, stream>>>(Wo, Wobf, VOC * HID / 8);
  conv_bf16_kernel<<<dim3(512), blk, 0, stream>>>(Wh, Wpbf, HID * HID / 8);
  conv_bf16_kernel<<<dim3(512), blk, 0, stream>>>(Wm, Wpbf + (size_t)HID * HID, HID * HID / 8);
  conv_bf16_kernel<<<dim3(512), blk, 0, stream>>>(Wc, Wpbf + (size_t)2 * HID * HID, HID * HID / 8);

  // projections (MFMA): HdT/MdT bf16 transposed + Cu fp32
  proj_mfma_kernel<<<dim3(32, 24), blk, 0, stream>>>(
      Hbf, Wpbf, bh, bm, bc, HdT, MdT, Cu);
  // GCN (MFMA) + tanh -> Gbf (bf16)
  gcn_mfma_kernel<<<dim3(32, 8), blk, 0, stream>>>(dep, HdT, MdT, Cu, Gbf);
  // fused MFMA vocab GEMM + online log-softmax partials
  loss_mfma_kernel<<<dim3(32, NPART), blk, 0, stream>>>(
      Gbf, Wobf, bo, tok, pm, ps_, pt_);
  // combine -> scalar loss
  combine_kernel<<<dim3(1), blk, 0, stream>>>(pm, ps_, pt_, out);
}

// Round 17
// 17117.053 us; speedup vs baseline: 1.8567x; 1.1736x over previous
//
#include <hip/hip_runtime.h>
#include <hip/hip_bf16.h>
#include <math.h>

#define S_LEN 4096
#define HID   1024
#define G4H   4096
#define EDIM  300
#define VOC   32000
#define NWG_LSTM 128
#define HPW   8           // h units per workgroup
#define NPART 25          // vocab parts for loss kernel (25 * 1280 = 32000)
#define NPCOL 50          // partial columns = NPART * 2 wave-halves

typedef __attribute__((ext_vector_type(8))) short bf16x8;
typedef __attribute__((ext_vector_type(4))) float f32x4;

__device__ __forceinline__ float bf_lo(unsigned u){ return __uint_as_float(u << 16); }
__device__ __forceinline__ float bf_hi(unsigned u){ return __uint_as_float(u & 0xffff0000u); }
__device__ __forceinline__ unsigned short f2bf(float x){
  unsigned u = __float_as_uint(x);
  unsigned r = (u + 0x7fffu + ((u >> 16) & 1u)) >> 16;
  return (unsigned short)r;
}

// ---------------------------------------------------------------------------
// fp32 -> bf16 conversion, 8 elems/thread
// ---------------------------------------------------------------------------
__global__ __launch_bounds__(256) void conv_bf16_kernel(
    const float* __restrict__ in, unsigned short* __restrict__ out, int n8)
{
  for (int i = blockIdx.x * blockDim.x + threadIdx.x; i < n8;
       i += gridDim.x * blockDim.x) {
    const float4* p = (const float4*)(in + (size_t)i * 8);
    float4 a = p[0], b = p[1];
    uint4 o;
    o.x = (unsigned)f2bf(a.x) | ((unsigned)f2bf(a.y) << 16);
    o.y = (unsigned)f2bf(a.z) | ((unsigned)f2bf(a.w) << 16);
    o.z = (unsigned)f2bf(b.x) | ((unsigned)f2bf(b.y) << 16);
    o.w = (unsigned)f2bf(b.z) | ((unsigned)f2bf(b.w) << 16);
    *(uint4*)(out + (size_t)i * 8) = o;
  }
}

// tagged-u64 h -> bf16 (low 32 bits hold the f32)
__global__ __launch_bounds__(256) void conv_h_bf16_kernel(
    const unsigned long long* __restrict__ in, unsigned short* __restrict__ out,
    int n8)
{
  for (int i = blockIdx.x * blockDim.x + threadIdx.x; i < n8;
       i += gridDim.x * blockDim.x) {
    const ulonglong2* p = (const ulonglong2*)(in + (size_t)i * 8);
    ulonglong2 q0 = p[0], q1 = p[1], q2 = p[2], q3 = p[3];
    uint4 o;
    o.x = (unsigned)f2bf(__uint_as_float((unsigned)q0.x)) |
          ((unsigned)f2bf(__uint_as_float((unsigned)q0.y)) << 16);
    o.y = (unsigned)f2bf(__uint_as_float((unsigned)q1.x)) |
          ((unsigned)f2bf(__uint_as_float((unsigned)q1.y)) << 16);
    o.z = (unsigned)f2bf(__uint_as_float((unsigned)q2.x)) |
          ((unsigned)f2bf(__uint_as_float((unsigned)q2.y)) << 16);
    o.w = (unsigned)f2bf(__uint_as_float((unsigned)q3.x)) |
          ((unsigned)f2bf(__uint_as_float((unsigned)q3.y)) << 16);
    *(uint4*)(out + (size_t)i * 8) = o;
  }
}

// ---------------------------------------------------------------------------
// Generic C = A @ B^T + bias1 (+bias2), A rows optionally gathered. (Gx only)
// ---------------------------------------------------------------------------
template<int BM, int BN, int BK, int TM, int TN, bool GATHER, bool HASB2>
__global__ __launch_bounds__(256) void gemm_abt(
    const float* __restrict__ A, int lda, const int* __restrict__ gidx,
    const float* __restrict__ B, int ldb,
    const float* __restrict__ bias1, const float* __restrict__ bias2,
    float* __restrict__ C, int ldc, int K)
{
  __shared__ float As[BK][BM + 1];
  __shared__ float Bs[BK][BN + 1];
  const int tid = threadIdx.x;
  const int tx = tid & 15, ty = tid >> 4;
  const int m0 = blockIdx.x * BM, n0 = blockIdx.y * BN;

  float acc[TM][TN];
#pragma unroll
  for (int i = 0; i < TM; i++)
#pragma unroll
    for (int j = 0; j < TN; j++) acc[i][j] = 0.f;

  for (int k0 = 0; k0 < K; k0 += BK) {
    for (int e = tid; e < BM * BK; e += 256) {
      int kk = e & (BK - 1); int m = e / BK;
      int k = k0 + kk;
      int row = GATHER ? gidx[m0 + m] : (m0 + m);
      As[kk][m] = (k < K) ? A[(size_t)row * lda + k] : 0.f;
    }
    for (int e = tid; e < BN * BK; e += 256) {
      int kk = e & (BK - 1); int n = e / BK;
      int k = k0 + kk;
      Bs[kk][n] = (k < K) ? B[(size_t)(n0 + n) * ldb + k] : 0.f;
    }
    __syncthreads();
#pragma unroll
    for (int kk = 0; kk < BK; kk++) {
      float a[TM], b[TN];
#pragma unroll
      for (int i = 0; i < TM; i++) a[i] = As[kk][ty + i * 16];
#pragma unroll
      for (int j = 0; j < TN; j++) b[j] = Bs[kk][tx + j * 16];
#pragma unroll
      for (int i = 0; i < TM; i++)
#pragma unroll
        for (int j = 0; j < TN; j++) acc[i][j] = fmaf(a[i], b[j], acc[i][j]);
    }
    __syncthreads();
  }
#pragma unroll
  for (int i = 0; i < TM; i++)
#pragma unroll
    for (int j = 0; j < TN; j++) {
      int m = m0 + ty + i * 16, n = n0 + tx + j * 16;
      float v = acc[i][j] + bias1[n];
      if (HASB2) v += bias2[n];
      C[(size_t)m * ldc + n] = v;
    }
}

// ---------------------------------------------------------------------------
// Persistent LSTM scan, cooperative launch. 128 WGs x 256 threads.
// TAGGED-H (r16-validated) + BARRIER-FREE waves (r17): each wave owns 2
// h-units END-TO-END (8 rows = 4 gates x 2 units in 64 VGPRs). After the
// full 64-lane butterfly, ALL lanes hold all 8 row-sums; lanes 0-1 finish
// their unit (4 gates, c-state in own regs, tanh) and publish tagged u64.
// NO __syncthreads, NO LDS: waves fully independent between global polls.
// ---------------------------------------------------------------------------
__global__ __launch_bounds__(256) void lstm_kernel(
    const float* __restrict__ Gx,          // [4096][4096] x-part + both biases
    const float* __restrict__ Whh,         // [4096][1024]
    unsigned long long* __restrict__ Hs2)  // [4096][1024] tagged h, zeroed
{
  const int wg = blockIdx.x;
  const int tid = threadIdx.x;
  const int w = tid >> 6;       // wave 0..3: owns h-units {wg*8+2w, wg*8+2w+1}
  const int lane = tid & 63;

  // rows r = g*2+u (g=gate 0..3, u=unit 0..1): row_id = g*1024 + wg*8 + 2w + u
  // pack matched to tagged-h layout: lane owns h[j*64+lane]
  unsigned wreg[64];
  {
#pragma unroll
    for (int g = 0; g < 4; g++)
#pragma unroll
      for (int u = 0; u < 2; u++) {
        int r = g * 2 + u;
        int row = g * HID + wg * HPW + 2 * w + u;
#pragma unroll
        for (int j = 0; j < 8; j++) {
          float w0 = Whh[(size_t)row * HID + (2 * j) * 64 + lane];
          float w1 = Whh[(size_t)row * HID + (2 * j + 1) * 64 + lane];
          wreg[r * 8 + j] = ((unsigned)f2bf(w1) << 16) | (unsigned)f2bf(w0);
        }
      }
  }
  float creg = 0.f;   // c-state: lane u (u<2) of each wave holds unit u's c

  for (int t = 0; t < S_LEN; t++) {
    // prefetch Gx for this wave's finisher lanes (in flight during poll)
    float gx0 = 0.f, gx1 = 0.f, gx2 = 0.f, gx3 = 0.f;
    if (lane < 2) {
      size_t b = (size_t)t * G4H + wg * HPW + 2 * w + lane;
      gx0 = Gx[b];
      gx1 = Gx[b + 1024];
      gx2 = Gx[b + 2048];
      gx3 = Gx[b + 3072];
    }

    float hv[16];
    if (t > 0) {
      const unsigned long long* hp = Hs2 + (size_t)(t - 1) * HID;
      unsigned long long hv64[16];
      while (true) {
        bool ok = true;
#pragma unroll
        for (int i = 0; i < 16; i++) {
          hv64[i] = __hip_atomic_load(&hp[i * 64 + lane], __ATOMIC_RELAXED,
                                      __HIP_MEMORY_SCOPE_AGENT);
          ok &= ((unsigned)(hv64[i] >> 32) == (unsigned)t);
        }
        if (__all(ok)) break;
        __builtin_amdgcn_s_sleep(1);
      }
      asm volatile("" ::: "memory");
#pragma unroll
      for (int i = 0; i < 16; i++) hv[i] = __uint_as_float((unsigned)hv64[i]);
    } else {
#pragma unroll
      for (int i = 0; i < 16; i++) hv[i] = 0.f;
    }

    float rsum[8];
#pragma unroll
    for (int r = 0; r < 8; r++) {
      float acc = 0.f;
#pragma unroll
      for (int j = 0; j < 8; j++) {
        unsigned wv = wreg[r * 8 + j];
        acc = fmaf(bf_lo(wv), hv[2 * j], acc);
        acc = fmaf(bf_hi(wv), hv[2 * j + 1], acc);
      }
#pragma unroll
      for (int off = 1; off < 64; off <<= 1) acc += __shfl_xor(acc, off, 64);
      rsum[r] = acc;   // all lanes hold the total
    }

    // lanes 0-1 finish their unit: gates are rows {u, 2+u, 4+u, 6+u}
    if (lane < 2) {
      float gi = rsum[0 + lane] + gx0;
      float gf = rsum[2 + lane] + gx1;
      float gg = rsum[4 + lane] + gx2;
      float go = rsum[6 + lane] + gx3;
      float i_ = 1.f / (1.f + expf(-gi));
      float f_ = 1.f / (1.f + expf(-gf));
      float g_ = tanhf(gg);
      float o_ = 1.f / (1.f + expf(-go));
      float c = f_ * creg + i_ * g_;
      creg = c;
      float h = o_ * tanhf(c);
      unsigned long long pkt = (unsigned long long)__float_as_uint(h) |
                               ((unsigned long long)(unsigned)(t + 1) << 32);
      __hip_atomic_store(&Hs2[(size_t)t * HID + wg * HPW + 2 * w + lane], pkt,
                         __ATOMIC_RELAXED, __HIP_MEMORY_SCOPE_AGENT);
    }
    // no barrier, no flag, no drain: waves are fully independent
  }
}

// ---------------------------------------------------------------------------
// MFMA projections: C[m][n] = Hbf[m][:] . Wpbf[n][:], m=seq 4096, n=0..3071
// ---------------------------------------------------------------------------
__global__ __launch_bounds__(256) void proj_mfma_kernel(
    const unsigned short* __restrict__ Hbf,   // [4096][1024]
    const unsigned short* __restrict__ Wpbf,  // [3072][1024]
    const float* __restrict__ bh, const float* __restrict__ bm,
    const float* __restrict__ bc,
    unsigned short* __restrict__ HdT,         // [1024][4096] bf16
    unsigned short* __restrict__ MdT,         // [1024][4096] bf16
    float* __restrict__ Cu)                   // [4096][1024] fp32
{
  __shared__ unsigned short As[128 * 72];
  __shared__ unsigned short Bs[128 * 72];
  const int tid = threadIdx.x;
  const int lane = tid & 63;
  const int wid = tid >> 6;
  const int wm = wid >> 1, wn = wid & 1;
  const int lrow = lane & 15, lkg = lane >> 4;
  const int i0 = blockIdx.x * 128;
  const int nb = blockIdx.y;            // 0..23
  const int n0 = nb * 128;              // row into Wpbf
  const int seg = nb >> 3;              // 0:Wh 1:Wm 2:Wc
  const int nloc0 = (nb & 7) * 128;     // col base within segment

  f32x4 acc[4][4];
#pragma unroll
  for (int mt = 0; mt < 4; mt++)
#pragma unroll
    for (int nt = 0; nt < 4; nt++) acc[mt][nt] = (f32x4){0.f, 0.f, 0.f, 0.f};

  for (int k0 = 0; k0 < HID; k0 += 64) {
#pragma unroll
    for (int it = 0; it < 4; it++) {
      int idx = it * 256 + tid;
      int row = idx >> 3, col8 = (idx & 7) * 8;
      *(uint4*)&As[row * 72 + col8] =
          *(const uint4*)&Hbf[(size_t)(i0 + row) * HID + k0 + col8];
      *(uint4*)&Bs[row * 72 + col8] =
          *(const uint4*)&Wpbf[(size_t)(n0 + row) * HID + k0 + col8];
    }
    __syncthreads();
#pragma unroll
    for (int ks = 0; ks < 2; ks++) {
      const int kk = ks * 32 + lkg * 8;
      bf16x8 a[4], b[4];
#pragma unroll
      for (int mt = 0; mt < 4; mt++)
        a[mt] = *(const bf16x8*)&As[(wm * 64 + mt * 16 + lrow) * 72 + kk];
#pragma unroll
      for (int nt = 0; nt < 4; nt++)
        b[nt] = *(const bf16x8*)&Bs[(wn * 64 + nt * 16 + lrow) * 72 + kk];
#pragma unroll
      for (int mt = 0; mt < 4; mt++)
#pragma unroll
        for (int nt = 0; nt < 4; nt++)
          acc[mt][nt] = __builtin_amdgcn_mfma_f32_16x16x32_bf16(
              a[mt], b[nt], acc[mt][nt], 0, 0, 0);
    }
    __syncthreads();
  }

  const float* bias = (seg == 0) ? bh : ((seg == 1) ? bm : bc);
  unsigned short* T = (seg == 0) ? HdT : MdT;
#pragma unroll
  for (int mt = 0; mt < 4; mt++)
#pragma unroll
    for (int nt = 0; nt < 4; nt++) {
      int nl = nloc0 + wn * 64 + nt * 16 + lrow;
      float bv = bias[nl];
      int mbase = i0 + wm * 64 + mt * 16 + lkg * 4;
      if (seg == 2) {
#pragma unroll
        for (int r = 0; r < 4; r++)
          Cu[(size_t)(mbase + r) * HID + nl] = acc[mt][nt][r] + bv;
      } else {
        unsigned v0 = (unsigned)f2bf(acc[mt][nt][0] + bv) |
                      ((unsigned)f2bf(acc[mt][nt][1] + bv) << 16);
        unsigned v1 = (unsigned)f2bf(acc[mt][nt][2] + bv) |
                      ((unsigned)f2bf(acc[mt][nt][3] + bv) << 16);
        uint2 pk; pk.x = v0; pk.y = v1;
        *(uint2*)&T[(size_t)nl * S_LEN + mbase] = pk;
      }
    }
}

// ---------------------------------------------------------------------------
// MFMA GCN: Gbf[i][d] = bf16(tanh(Cu[i][d]
//            + sum_{j<i} dep[j][i]*Hd[j][d] + sum_{j<i} dep[i][j]*Md[j][d]))
// ---------------------------------------------------------------------------
__global__ __launch_bounds__(256) void gcn_mfma_kernel(
    const float* __restrict__ dep,            // [4097][4097]
    const unsigned short* __restrict__ HdT,   // [1024][4096]
    const unsigned short* __restrict__ MdT,   // [1024][4096]
    const float* __restrict__ Cu,             // [4096][1024]
    unsigned short* __restrict__ Gbf)         // [4096][1024] bf16
{
  __shared__ unsigned short As1[128 * 72];
  __shared__ unsigned short As2[128 * 72];
  __shared__ unsigned short Bs1[128 * 72];
  __shared__ unsigned short Bs2[128 * 72];
  const int tid = threadIdx.x;
  const int lane = tid & 63;
  const int wid = tid >> 6;
  const int wm = wid >> 1, wn = wid & 1;
  const int lrow = lane & 15, lkg = lane >> 4;
  const int i0 = blockIdx.x * 128;
  const int d0 = blockIdx.y * 128;

  f32x4 acc[4][4];
#pragma unroll
  for (int mt = 0; mt < 4; mt++)
#pragma unroll
    for (int nt = 0; nt < 4; nt++) acc[mt][nt] = (f32x4){0.f, 0.f, 0.f, 0.f};

  const int jmax = i0 + 128;
  for (int j0 = 0; j0 < jmax; j0 += 64) {
    for (int e = tid; e < 128 * 64; e += 256) {
      int ii = e & 127, jj = e >> 7;
      int j = j0 + jj, i = i0 + ii;
      As1[ii * 72 + jj] = (j < i) ? f2bf(dep[(size_t)j * (S_LEN + 1) + i])
                                  : (unsigned short)0;
    }
    for (int e = tid; e < 128 * 64; e += 256) {
      int jj = e & 63, ii = e >> 6;
      int j = j0 + jj, i = i0 + ii;
      As2[ii * 72 + jj] = (j < i) ? f2bf(dep[(size_t)i * (S_LEN + 1) + j])
                                  : (unsigned short)0;
    }
    for (int e = tid; e < 128 * 8; e += 256) {
      int row = e >> 3, col8 = (e & 7) * 8;
      *(uint4*)&Bs1[row * 72 + col8] =
          *(const uint4*)&HdT[(size_t)(d0 + row) * S_LEN + j0 + col8];
      *(uint4*)&Bs2[row * 72 + col8] =
          *(const uint4*)&MdT[(size_t)(d0 + row) * S_LEN + j0 + col8];
    }
    __syncthreads();
#pragma unroll
    for (int ks = 0; ks < 2; ks++) {
      const int kk = ks * 32 + lkg * 8;
      bf16x8 a1[4], a2[4], b1[4], b2[4];
#pragma unroll
      for (int mt = 0; mt < 4; mt++) {
        a1[mt] = *(const bf16x8*)&As1[(wm * 64 + mt * 16 + lrow) * 72 + kk];
        a2[mt] = *(const bf16x8*)&As2[(wm * 64 + mt * 16 + lrow) * 72 + kk];
      }
#pragma unroll
      for (int nt = 0; nt < 4; nt++) {
        b1[nt] = *(const bf16x8*)&Bs1[(wn * 64 + nt * 16 + lrow) * 72 + kk];
        b2[nt] = *(const bf16x8*)&Bs2[(wn * 64 + nt * 16 + lrow) * 72 + kk];
      }
#pragma unroll
      for (int mt = 0; mt < 4; mt++)
#pragma unroll
        for (int nt = 0; nt < 4; nt++) {
          acc[mt][nt] = __builtin_amdgcn_mfma_f32_16x16x32_bf16(
              a1[mt], b1[nt], acc[mt][nt], 0, 0, 0);
          acc[mt][nt] = __builtin_amdgcn_mfma_f32_16x16x32_bf16(
              a2[mt], b2[nt], acc[mt][nt], 0, 0, 0);
        }
    }
    __syncthreads();
  }

#pragma unroll
  for (int mt = 0; mt < 4; mt++)
#pragma unroll
    for (int nt = 0; nt < 4; nt++) {
      int n = d0 + wn * 64 + nt * 16 + lrow;
#pragma unroll
      for (int r = 0; r < 4; r++) {
        int m = i0 + wm * 64 + mt * 16 + lkg * 4 + r;
        float vv = acc[mt][nt][r] + Cu[(size_t)m * HID + n];
        Gbf[(size_t)m * HID + n] = f2bf(tanhf(vv));
      }
    }
}

// ---------------------------------------------------------------------------
// MFMA bf16 fused vocab GEMM + online log-softmax partials. (validated)
// ---------------------------------------------------------------------------
__global__ __launch_bounds__(256) void loss_mfma_kernel(
    const unsigned short* __restrict__ Gbf,   // [4096][1024] bf16
    const unsigned short* __restrict__ Wobf,  // [32000][1024] bf16
    const float* __restrict__ bo, const int* __restrict__ tokens,
    float* __restrict__ pm, float* __restrict__ ps, float* __restrict__ pt)
{
  __shared__ unsigned short As[128 * 72];
  __shared__ unsigned short Bs[128 * 72];
  const int tid = threadIdx.x;
  const int lane = tid & 63;
  const int wid = tid >> 6;
  const int wm = wid >> 1;
  const int wn = wid & 1;
  const int lrow = lane & 15;
  const int lkg  = lane >> 4;
  const int i0 = blockIdx.x * 128;
  const int part = blockIdx.y;
  const int nbase = part * 1280;

  float rmax[4][4], rsum[4][4], tsum[4][4];
  int tg[4][4];
#pragma unroll
  for (int mt = 0; mt < 4; mt++)
#pragma unroll
    for (int r = 0; r < 4; r++) {
      rmax[mt][r] = -1e30f; rsum[mt][r] = 0.f; tsum[mt][r] = 0.f;
      tg[mt][r] = tokens[1 + i0 + wm * 64 + mt * 16 + lkg * 4 + r];
    }

  for (int c = 0; c < 10; c++) {
    const int n0 = nbase + c * 128;
    f32x4 acc[4][4];
#pragma unroll
    for (int mt = 0; mt < 4; mt++)
#pragma unroll
      for (int nt = 0; nt < 4; nt++) acc[mt][nt] = (f32x4){0.f, 0.f, 0.f, 0.f};

    for (int k0 = 0; k0 < HID; k0 += 64) {
#pragma unroll
      for (int it = 0; it < 4; it++) {
        int idx = it * 256 + tid;
        int row = idx >> 3, col8 = (idx & 7) * 8;
        *(uint4*)&As[row * 72 + col8] =
            *(const uint4*)&Gbf[(size_t)(i0 + row) * HID + k0 + col8];
        *(uint4*)&Bs[row * 72 + col8] =
            *(const uint4*)&Wobf[(size_t)(n0 + row) * HID + k0 + col8];
      }
      __syncthreads();
#pragma unroll
      for (int ks = 0; ks < 2; ks++) {
        const int kk = ks * 32 + lkg * 8;
        bf16x8 a[4], b[4];
#pragma unroll
        for (int mt = 0; mt < 4; mt++)
          a[mt] = *(const bf16x8*)&As[(wm * 64 + mt * 16 + lrow) * 72 + kk];
#pragma unroll
        for (int nt = 0; nt < 4; nt++)
          b[nt] = *(const bf16x8*)&Bs[(wn * 64 + nt * 16 + lrow) * 72 + kk];
#pragma unroll
        for (int mt = 0; mt < 4; mt++)
#pragma unroll
          for (int nt = 0; nt < 4; nt++)
            acc[mt][nt] = __builtin_amdgcn_mfma_f32_16x16x32_bf16(
                a[mt], b[nt], acc[mt][nt], 0, 0, 0);
      }
      __syncthreads();
    }

    float bov[4];
#pragma unroll
    for (int nt = 0; nt < 4; nt++)
      bov[nt] = bo[n0 + wn * 64 + nt * 16 + lrow];

#pragma unroll
    for (int mt = 0; mt < 4; mt++)
#pragma unroll
      for (int r = 0; r < 4; r++) {
        float v0 = acc[mt][0][r] + bov[0];
        float v1 = acc[mt][1][r] + bov[1];
        float v2 = acc[mt][2][r] + bov[2];
        float v3 = acc[mt][3][r] + bov[3];
        float cm = fmaxf(fmaxf(v0, v1), fmaxf(v2, v3));
#pragma unroll
        for (int off = 1; off < 16; off <<= 1) cm = fmaxf(cm, __shfl_xor(cm, off, 64));
        float nm = fmaxf(rmax[mt][r], cm);
        float sp = __expf(v0 - nm) + __expf(v1 - nm) + __expf(v2 - nm) + __expf(v3 - nm);
#pragma unroll
        for (int off = 1; off < 16; off <<= 1) sp += __shfl_xor(sp, off, 64);
        rsum[mt][r] = rsum[mt][r] * __expf(rmax[mt][r] - nm) + sp;
        rmax[mt][r] = nm;
        int nc = n0 + wn * 64 + lrow;
        if (nc       == tg[mt][r]) tsum[mt][r] += v0;
        if (nc + 16  == tg[mt][r]) tsum[mt][r] += v1;
        if (nc + 32  == tg[mt][r]) tsum[mt][r] += v2;
        if (nc + 48  == tg[mt][r]) tsum[mt][r] += v3;
      }
  }

  const int p = part * 2 + wn;
#pragma unroll
  for (int mt = 0; mt < 4; mt++)
#pragma unroll
    for (int r = 0; r < 4; r++) {
      float tv = tsum[mt][r];
#pragma unroll
      for (int off = 1; off < 16; off <<= 1) tv += __shfl_xor(tv, off, 64);
      if (lrow == 0) {
        int m = i0 + wm * 64 + mt * 16 + lkg * 4 + r;
        pm[p * S_LEN + m] = rmax[mt][r];
        ps[p * S_LEN + m] = rsum[mt][r];
        pt[p * S_LEN + m] = tv;
      }
    }
}

// ---------------------------------------------------------------------------
// Combine partials across the NPCOL column-partials -> mean NLL
// ---------------------------------------------------------------------------
__global__ __launch_bounds__(256) void combine_kernel(
    const float* __restrict__ pm, const float* __restrict__ ps,
    const float* __restrict__ pt, float* __restrict__ out)
{
  const int tid = threadIdx.x;
  float lsum = 0.f;
  for (int r = tid; r < S_LEN; r += 256) {
    float M = -1e30f;
    for (int p = 0; p < NPCOL; p++) M = fmaxf(M, pm[p * S_LEN + r]);
    float S = 0.f, tv = 0.f;
    for (int p = 0; p < NPCOL; p++) {
      S += ps[p * S_LEN + r] * expf(pm[p * S_LEN + r] - M);
      tv += pt[p * S_LEN + r];
    }
    lsum += (M + logf(S)) - tv;
  }
  __shared__ float red[256];
  red[tid] = lsum;
  __syncthreads();
  for (int s = 128; s > 0; s >>= 1) {
    if (tid < s) red[tid] += red[tid + s];
    __syncthreads();
  }
  if (tid == 0) out[0] = red[0] / (float)S_LEN;
}

// ---------------------------------------------------------------------------
extern "C" void kernel_launch(void* const* d_in, const int* in_sizes, int n_in,
                              void* d_out, int out_size, void* d_ws, size_t ws_size,
                              hipStream_t stream)
{
  const float* dep = (const float*)d_in[0];
  const float* emb = (const float*)d_in[1];
  const float* Wih = (const float*)d_in[2];
  const float* Whh = (const float*)d_in[3];
  const float* bih = (const float*)d_in[4];
  const float* bhh = (const float*)d_in[5];
  const float* Wh  = (const float*)d_in[6];
  const float* bh  = (const float*)d_in[7];
  const float* Wm  = (const float*)d_in[8];
  const float* bm  = (const float*)d_in[9];
  const float* Wc  = (const float*)d_in[10];
  const float* bc  = (const float*)d_in[11];
  const float* Wo  = (const float*)d_in[12];
  const float* bo  = (const float*)d_in[13];
  const int*   tok = (const int*)d_in[14];
  float* out = (float*)d_out;

  float* ws = (float*)d_ws;
  size_t o = 0;
  float* Gx = ws + o; o += (size_t)S_LEN * G4H;              // 67 MB; Wobf alias
  unsigned long long* Hs2 = (unsigned long long*)(ws + o);   // 32 MB tagged h
  float* aliasBase = ws + o; o += (size_t)S_LEN * HID * 2;
  float* Cu = ws + o; o += (size_t)S_LEN * HID;
  float* pm = ws + o; o += (size_t)NPCOL * S_LEN;
  float* ps_ = ws + o; o += (size_t)NPCOL * S_LEN;
  float* pt_ = ws + o; o += (size_t)NPCOL * S_LEN;
  unsigned short* Hbf = (unsigned short*)(ws + o); o += (size_t)S_LEN * HID / 2;
  // buffers that alias Hs2 AFTER it is dead (post Hbf-extraction):
  unsigned short* Wpbf = (unsigned short*)aliasBase;
  unsigned short* HdT  = (unsigned short*)(aliasBase + (size_t)3 * HID * HID / 2);
  unsigned short* MdT  = HdT + (size_t)S_LEN * HID;
  unsigned short* Gbf  = MdT + (size_t)S_LEN * HID;
  // Wobf aliases Gx (65.5 MB <= 67 MB), written only after lstm_kernel finished
  unsigned short* Wobf = (unsigned short*)Gx;

  // zero the tagged-h buffer each launch: tags must start != any t in [1,4096]
  hipMemsetAsync(Hs2, 0, (size_t)S_LEN * HID * 8, stream);

  dim3 blk(256);
  // Gx = emb[tok] @ W_ih^T + b_ih + b_hh
  gemm_abt<128, 128, 16, 8, 8, true, true><<<dim3(32, 32), blk, 0, stream>>>(
      emb, EDIM, tok, Wih, EDIM, bih, bhh, Gx, G4H, EDIM);

  // sequential LSTM — cooperative launch, tagged-h + barrier-free waves
  {
    void* args[] = {(void*)&Gx, (void*)&Whh, (void*)&Hs2};
    hipLaunchCooperativeKernel((const void*)lstm_kernel, dim3(NWG_LSTM),
                               dim3(256), args, 0, stream);
  }

  // conversions (order matters: Hbf from Hs2 BEFORE anything aliases Hs2)
  conv_h_bf16_kernel<<<dim3(512), blk, 0, stream>>>(Hs2, Hbf, S_LEN * HID / 8);
  conv_bf16_kernel<<<dim3(2048), blk, 0, stream>>>(Wo, Wobf, VOC * HID / 8);
  conv_bf16_kernel<<<dim3(512), blk, 0, stream>>>(Wh, Wpbf, HID * HID / 8);
  conv_bf16_kernel<<<dim3(512), blk, 0, stream>>>(Wm, Wpbf + (size_t)HID * HID, HID * HID / 8);
  conv_bf16_kernel<<<dim3(512), blk, 0, stream>>>(Wc, Wpbf + (size_t)2 * HID * HID, HID * HID / 8);

  // projections (MFMA): HdT/MdT bf16 transposed + Cu fp32
  proj_mfma_kernel<<<dim3(32, 24), blk, 0, stream>>>(
      Hbf, Wpbf, bh, bm, bc, HdT, MdT, Cu);
  // GCN (MFMA) + tanh -> Gbf (bf16)
  gcn_mfma_kernel<<<dim3(32, 8), blk, 0, stream>>>(dep, HdT, MdT, Cu, Gbf);
  // fused MFMA vocab GEMM + online log-softmax partials
  loss_mfma_kernel<<<dim3(32, NPART), blk, 0, stream>>>(
      Gbf, Wobf, bo, tok, pm, ps_, pt_);
  // combine -> scalar loss
  combine_kernel<<<dim3(1), blk, 0, stream>>>(pm, ps_, pt_, out);
}